// Round 2
// baseline (953.385 us; speedup 1.0000x reference)
//
#include <hip/hip_runtime.h>
#include <hip/hip_bf16.h>
#include <math.h>

#define B_      4
#define SD_     2048
#define SE_     2048
#define HIDIN   300
#define HIDMID  512
#define NH      8
#define DH      64

// floats per Q/K/V/AO buffer in workspace
#define QSZ ((size_t)B_ * NH * SD_ * DH)   // 4,194,304 floats = 16.78 MB

// ---------------------------------------------------------------------------
// Kernel 1: fused QKV projection.
// A[8192,300] @ W[300,512] -> head-split layout out[(b*8+h)][s][d], col j = d*8+h.
// grid (128 row-tiles, 8 col-tiles, 3 which), block 256.
// ---------------------------------------------------------------------------
__global__ __launch_bounds__(256) void proj_kernel(
    const float* __restrict__ de, const float* __restrict__ en,
    const float* __restrict__ WQ, const float* __restrict__ WK,
    const float* __restrict__ WV, float* __restrict__ ws)
{
    const int which = blockIdx.z;
    const float* __restrict__ A = (which == 0) ? de : en;
    const float* __restrict__ W = (which == 0) ? WQ : (which == 1 ? WK : WV);
    float* __restrict__ out = ws + (size_t)which * QSZ;

    const int row0 = blockIdx.x * 64;
    const int c0   = blockIdx.y * 64;

    __shared__ float At[64][65];   // [kk][row] transposed (stride 65: conflict-free)
    __shared__ float Bs[64][65];   // [kk][col]

    const int tid = threadIdx.x;
    const int tx = tid & 15, ty = tid >> 4;

    float acc[4][4];
#pragma unroll
    for (int i = 0; i < 4; ++i)
#pragma unroll
        for (int j = 0; j < 4; ++j) acc[i][j] = 0.f;

    for (int kc = 0; kc < HIDIN; kc += 64) {
        __syncthreads();
#pragma unroll
        for (int it = 0; it < 16; ++it) {
            int idx = tid + it * 256;
            int r  = idx >> 6;
            int kk = idx & 63;
            float av = (kc + kk < HIDIN) ? A[(size_t)(row0 + r) * HIDIN + kc + kk] : 0.f;
            At[kk][r] = av;
            // reuse idx for B: kk2 = r position, c = kk position
            int kk2 = idx >> 6;
            int c   = idx & 63;
            float bv = (kc + kk2 < HIDIN) ? W[(size_t)(kc + kk2) * HIDMID + c0 + c] : 0.f;
            Bs[kk2][c] = bv;
        }
        __syncthreads();
#pragma unroll 8
        for (int kk = 0; kk < 64; ++kk) {
            float a[4], b[4];
#pragma unroll
            for (int i = 0; i < 4; ++i) a[i] = At[kk][ty * 4 + i];
#pragma unroll
            for (int j = 0; j < 4; ++j) b[j] = Bs[kk][tx * 4 + j];
#pragma unroll
            for (int i = 0; i < 4; ++i)
#pragma unroll
                for (int j = 0; j < 4; ++j)
                    acc[i][j] = fmaf(a[i], b[j], acc[i][j]);
        }
    }

#pragma unroll
    for (int i = 0; i < 4; ++i) {
        int r  = row0 + ty * 4 + i;
        int bb = r >> 11;          // /2048
        int s  = r & 2047;
#pragma unroll
        for (int j = 0; j < 4; ++j) {
            int jg = c0 + tx * 4 + j;
            int d  = jg >> 3;
            int hh = jg & 7;
            out[(((size_t)(bb * NH + hh)) * SD_ + s) * DH + d] = acc[i][j];
        }
    }
}

// ---------------------------------------------------------------------------
// Kernel 2: flash attention (fp32). grid (32 q-tiles, 32 bh), block 256.
// Per block: 64 Q-rows x full SE loop in 64-wide K/V tiles.
// mask is int32 (reference bool -> harness int).
// ---------------------------------------------------------------------------
__global__ __launch_bounds__(256) void attn_kernel(
    const float* __restrict__ ws, const int* __restrict__ mask,
    float* __restrict__ AO)
{
    const int qt = blockIdx.x;
    const int bh = blockIdx.y;
    const int bb = bh >> 3, hh = bh & 7;
    const int q0 = qt * 64;

    const float* __restrict__ Q = ws + (size_t)bh * SD_ * DH;
    const float* __restrict__ K = ws + QSZ + (size_t)bh * SE_ * DH;
    const float* __restrict__ V = ws + 2 * QSZ + (size_t)bh * SE_ * DH;

    __shared__ float Qt[64][65];    // transposed Q tile [d][q]
    __shared__ float KtP[64][65];   // K transposed [d][t]; reused for P [q][t]
    __shared__ float Vs[64][64];    // V row-major [t][d]

    const int tid = threadIdx.x;
    const int tx = tid & 15, ty = tid >> 4;

#pragma unroll
    for (int it = 0; it < 16; ++it) {
        int idx = tid + it * 256;
        int r = idx >> 6, d = idx & 63;
        Qt[d][r] = Q[(size_t)(q0 + r) * DH + d];
    }

    float m[4], l[4], O[4][4];
#pragma unroll
    for (int i = 0; i < 4; ++i) {
        m[i] = -INFINITY;
        l[i] = 0.f;
#pragma unroll
        for (int j = 0; j < 4; ++j) O[i][j] = 0.f;
    }

    const float scale = 0.057735026918962584f;  // 1/sqrt(300)

    for (int kt0 = 0; kt0 < SE_; kt0 += 64) {
        __syncthreads();   // prior P/V reads complete
#pragma unroll
        for (int it = 0; it < 16; ++it) {
            int idx = tid + it * 256;
            int r = idx >> 6, d = idx & 63;
            float kv = K[(size_t)(kt0 + r) * DH + d];
            KtP[d][r] = kv;
            Vs[r][d]  = V[(size_t)(kt0 + r) * DH + d];
        }
        __syncthreads();

        // ---- S = Q K^T ----
        float s[4][4];
#pragma unroll
        for (int i = 0; i < 4; ++i)
#pragma unroll
            for (int j = 0; j < 4; ++j) s[i][j] = 0.f;
#pragma unroll 8
        for (int kk = 0; kk < 64; ++kk) {
            float a[4], b[4];
#pragma unroll
            for (int i = 0; i < 4; ++i) a[i] = Qt[kk][ty * 4 + i];
#pragma unroll
            for (int j = 0; j < 4; ++j) b[j] = KtP[kk][tx * 4 + j];
#pragma unroll
            for (int i = 0; i < 4; ++i)
#pragma unroll
                for (int j = 0; j < 4; ++j)
                    s[i][j] = fmaf(a[i], b[j], s[i][j]);
        }

        // ---- scale + mask (mask TRUE -> -1e9, matching reference) ----
#pragma unroll
        for (int i = 0; i < 4; ++i) {
            const size_t mbase = (size_t)(q0 + ty * 4 + i) * SE_ + kt0 + tx * 4;
#pragma unroll
            for (int j = 0; j < 4; ++j)
                s[i][j] = mask[mbase + j] ? -1e9f : s[i][j] * scale;
        }

        // ---- online softmax (row shared by 16 contiguous lanes) ----
        float pf[4];
#pragma unroll
        for (int i = 0; i < 4; ++i) {
            float tmax = fmaxf(fmaxf(s[i][0], s[i][1]), fmaxf(s[i][2], s[i][3]));
#pragma unroll
            for (int off = 8; off; off >>= 1)
                tmax = fmaxf(tmax, __shfl_xor(tmax, off));
            float mn = fmaxf(m[i], tmax);
            pf[i] = __expf(m[i] - mn);   // exp(-inf)=0 on first tile
            m[i]  = mn;
            float ps = 0.f;
#pragma unroll
            for (int j = 0; j < 4; ++j) {
                float p = __expf(s[i][j] - mn);
                s[i][j] = p;
                ps += p;
            }
#pragma unroll
            for (int off = 8; off; off >>= 1)
                ps += __shfl_xor(ps, off);
            l[i] = l[i] * pf[i] + ps;
        }

        __syncthreads();   // everyone done reading Kt
        // write P into KtP buffer (row-major [q][t]); rescale O in registers
#pragma unroll
        for (int i = 0; i < 4; ++i) {
#pragma unroll
            for (int j = 0; j < 4; ++j) {
                KtP[ty * 4 + i][tx * 4 + j] = s[i][j];
                O[i][j] *= pf[i];
            }
        }
        __syncthreads();

        // ---- O += P V ----
#pragma unroll 8
        for (int kk = 0; kk < 64; ++kk) {
            float p[4], v[4];
#pragma unroll
            for (int i = 0; i < 4; ++i) p[i] = KtP[ty * 4 + i][kk];
#pragma unroll
            for (int j = 0; j < 4; ++j) v[j] = Vs[kk][tx * 4 + j];
#pragma unroll
            for (int i = 0; i < 4; ++i)
#pragma unroll
                for (int j = 0; j < 4; ++j)
                    O[i][j] = fmaf(p[i], v[j], O[i][j]);
        }
    }

    // ---- normalize + store AO[b][s][h][d] (concat layout for epilogue) ----
#pragma unroll
    for (int i = 0; i < 4; ++i) {
        int srow = q0 + ty * 4 + i;
        float rl = 1.f / l[i];
        float4 o4 = make_float4(O[i][0] * rl, O[i][1] * rl, O[i][2] * rl, O[i][3] * rl);
        *(float4*)&AO[(((size_t)(bb * SD_ + srow)) * NH + hh) * DH + tx * 4] = o4;
    }
}

// ---------------------------------------------------------------------------
// Kernel 3: epilogue GEMM AO[8192,512] @ WO[512,300] -> out[8192,300].
// grid (128, 5), block 256.
// ---------------------------------------------------------------------------
__global__ __launch_bounds__(256) void epi_kernel(
    const float* __restrict__ AO, const float* __restrict__ WO,
    float* __restrict__ out)
{
    const int row0 = blockIdx.x * 64;
    const int c0   = blockIdx.y * 64;

    __shared__ float At[64][65];
    __shared__ float Bs[64][65];

    const int tid = threadIdx.x;
    const int tx = tid & 15, ty = tid >> 4;

    float acc[4][4];
#pragma unroll
    for (int i = 0; i < 4; ++i)
#pragma unroll
        for (int j = 0; j < 4; ++j) acc[i][j] = 0.f;

    for (int kc = 0; kc < HIDMID; kc += 64) {
        __syncthreads();
#pragma unroll
        for (int it = 0; it < 16; ++it) {
            int idx = tid + it * 256;
            int r  = idx >> 6;
            int kk = idx & 63;
            At[kk][r] = AO[(size_t)(row0 + r) * HIDMID + kc + kk];
            int kk2 = idx >> 6;
            int c   = idx & 63;
            int cg  = c0 + c;
            Bs[kk2][c] = (cg < HIDIN) ? WO[(size_t)(kc + kk2) * HIDIN + cg] : 0.f;
        }
        __syncthreads();
#pragma unroll 8
        for (int kk = 0; kk < 64; ++kk) {
            float a[4], b[4];
#pragma unroll
            for (int i = 0; i < 4; ++i) a[i] = At[kk][ty * 4 + i];
#pragma unroll
            for (int j = 0; j < 4; ++j) b[j] = Bs[kk][tx * 4 + j];
#pragma unroll
            for (int i = 0; i < 4; ++i)
#pragma unroll
                for (int j = 0; j < 4; ++j)
                    acc[i][j] = fmaf(a[i], b[j], acc[i][j]);
        }
    }

#pragma unroll
    for (int i = 0; i < 4; ++i) {
        int r = row0 + ty * 4 + i;
#pragma unroll
        for (int j = 0; j < 4; ++j) {
            int o = c0 + tx * 4 + j;
            if (o < HIDIN) out[(size_t)r * HIDIN + o] = acc[i][j];
        }
    }
}

// ---------------------------------------------------------------------------
extern "C" void kernel_launch(void* const* d_in, const int* in_sizes, int n_in,
                              void* d_out, int out_size, void* d_ws, size_t ws_size,
                              hipStream_t stream)
{
    const float* en  = (const float*)d_in[0];
    const float* de  = (const float*)d_in[1];
    const int*   mask = (const int*)d_in[2];
    const float* WQ  = (const float*)d_in[3];
    const float* WK  = (const float*)d_in[4];
    const float* WV  = (const float*)d_in[5];
    const float* WO  = (const float*)d_in[6];
    float* out = (float*)d_out;
    float* ws  = (float*)d_ws;

    // ws layout: [Q | K | V | AO], each QSZ floats (67.1 MB total)
    proj_kernel<<<dim3(128, 8, 3), 256, 0, stream>>>(de, en, WQ, WK, WV, ws);
    attn_kernel<<<dim3(32, 32), 256, 0, stream>>>(ws, mask, ws + 3 * QSZ);
    epi_kernel<<<dim3(128, 5), 256, 0, stream>>>(ws + 3 * QSZ, WO, out);
}

// Round 3
// 783.388 us; speedup vs baseline: 1.2170x; 1.2170x over previous
//
#include <hip/hip_runtime.h>
#include <hip/hip_bf16.h>
#include <math.h>

#define B_      4
#define SD_     2048
#define SE_     2048
#define HIDIN   300
#define HIDMID  512
#define NH      8
#define DH      64
// elements per [32][2048][64] tensor (== 2048*2048)
#define ESZ     ((size_t)4194304)

typedef __attribute__((ext_vector_type(8))) short          s16x8;
typedef __attribute__((ext_vector_type(4))) short          s16x4;
typedef __attribute__((ext_vector_type(4))) unsigned short u16x4;
typedef __attribute__((ext_vector_type(4))) float          f32x4;

#define MFMA16 __builtin_amdgcn_mfma_f32_16x16x32_bf16

__device__ __forceinline__ unsigned short f2bf(float f) {
    unsigned int u = __float_as_uint(f);
    u += 0x7fffu + ((u >> 16) & 1u);          // RNE
    return (unsigned short)(u >> 16);
}
__device__ __forceinline__ float bf2f(unsigned short s) {
    return __uint_as_float((unsigned int)s << 16);
}

// ---------------------------------------------------------------------------
// Kernel 0: mask (int32) -> additive bias in bf16 {0, -1e9}
// ---------------------------------------------------------------------------
__global__ __launch_bounds__(256) void bias_kernel(const int* __restrict__ mask,
                                                   unsigned short* __restrict__ Bias)
{
    const int i = blockIdx.x * 256 + threadIdx.x;    // grid covers 2048*2048/4 exactly
    const int4 mm = ((const int4*)mask)[i];
    const unsigned short NEG = f2bf(-1e9f);
    u16x4 o;
    o[0] = mm.x ? NEG : (unsigned short)0;
    o[1] = mm.y ? NEG : (unsigned short)0;
    o[2] = mm.z ? NEG : (unsigned short)0;
    o[3] = mm.w ? NEG : (unsigned short)0;
    ((u16x4*)Bias)[i] = o;
}

// ---------------------------------------------------------------------------
// Kernel 1: fused QKV projection (fp32 math), outputs:
//   Q -> (scaled by 1/sqrt(300)) split bf16 Qh/Ql, layout [bh][s][d]
//   K -> split bf16 Kh/Kl, layout [bh][t][d]
//   V -> plain bf16 TRANSPOSED Vt[bh][d][t]
// head split: output col j of the 512-wide GEMM -> d = j>>3, h = j&7.
// ---------------------------------------------------------------------------
__global__ __launch_bounds__(256) void proj_kernel(
    const float* __restrict__ de, const float* __restrict__ en,
    const float* __restrict__ WQ, const float* __restrict__ WK,
    const float* __restrict__ WV,
    unsigned short* __restrict__ Qh, unsigned short* __restrict__ Ql,
    unsigned short* __restrict__ Kh, unsigned short* __restrict__ Kl,
    unsigned short* __restrict__ Vt)
{
    const int which = blockIdx.z;
    const float* __restrict__ A = (which == 0) ? de : en;
    const float* __restrict__ W = (which == 0) ? WQ : (which == 1 ? WK : WV);

    const int row0 = blockIdx.x * 64;
    const int c0   = blockIdx.y * 64;

    __shared__ float At[64][65];
    __shared__ float Bs[64][65];

    const int tid = threadIdx.x;
    const int tx = tid & 15, ty = tid >> 4;

    float acc[4][4];
#pragma unroll
    for (int i = 0; i < 4; ++i)
#pragma unroll
        for (int j = 0; j < 4; ++j) acc[i][j] = 0.f;

    for (int kc = 0; kc < HIDIN; kc += 64) {
        __syncthreads();
#pragma unroll
        for (int it = 0; it < 16; ++it) {
            int idx = tid + it * 256;
            int r  = idx >> 6;
            int kk = idx & 63;
            At[kk][r] = (kc + kk < HIDIN) ? A[(size_t)(row0 + r) * HIDIN + kc + kk] : 0.f;
            int kk2 = idx >> 6;
            int c   = idx & 63;
            Bs[kk2][c] = (kc + kk2 < HIDIN) ? W[(size_t)(kc + kk2) * HIDMID + c0 + c] : 0.f;
        }
        __syncthreads();
#pragma unroll 8
        for (int kk = 0; kk < 64; ++kk) {
            float a[4], b[4];
#pragma unroll
            for (int i = 0; i < 4; ++i) a[i] = At[kk][ty * 4 + i];
#pragma unroll
            for (int j = 0; j < 4; ++j) b[j] = Bs[kk][tx * 4 + j];
#pragma unroll
            for (int i = 0; i < 4; ++i)
#pragma unroll
                for (int j = 0; j < 4; ++j)
                    acc[i][j] = fmaf(a[i], b[j], acc[i][j]);
        }
    }

    const float scale = 0.057735026918962584f;  // 1/sqrt(300)
#pragma unroll
    for (int i = 0; i < 4; ++i) {
        int r  = row0 + ty * 4 + i;
        int bb = r >> 11;
        int s  = r & 2047;
#pragma unroll
        for (int j = 0; j < 4; ++j) {
            int jg = c0 + tx * 4 + j;
            int d  = jg >> 3;
            int hh = jg & 7;
            int bhn = bb * NH + hh;
            float val = acc[i][j];
            if (which == 0) {
                val *= scale;
                unsigned short hi = f2bf(val);
                unsigned short lo = f2bf(val - bf2f(hi));
                size_t o = ((size_t)bhn * SD_ + s) * DH + d;
                Qh[o] = hi; Ql[o] = lo;
            } else if (which == 1) {
                unsigned short hi = f2bf(val);
                unsigned short lo = f2bf(val - bf2f(hi));
                size_t o = ((size_t)bhn * SE_ + s) * DH + d;
                Kh[o] = hi; Kl[o] = lo;
            } else {
                Vt[((size_t)bhn * DH + d) * SE_ + s] = f2bf(val);
            }
        }
    }
}

// ---------------------------------------------------------------------------
// Kernel 2: MFMA flash attention. grid (32 q-tiles, 32 bh), block 256 = 4
// independent waves, 16 q-rows per wave. No LDS, no barriers.
//   S^T = mfma(K, Q)  (3-term split-bf16 error correction; bias as acc init)
//   O^T = mfma(V^T, P^T) with P^T kept in registers (sigma-consistent slots)
// ---------------------------------------------------------------------------
__global__ __launch_bounds__(256) void attn_mfma_kernel(
    const unsigned short* __restrict__ Qh, const unsigned short* __restrict__ Ql,
    const unsigned short* __restrict__ Kh, const unsigned short* __restrict__ Kl,
    const unsigned short* __restrict__ Vt, const unsigned short* __restrict__ Bias,
    float* __restrict__ AO)
{
    const int qt = blockIdx.x, bh = blockIdx.y;
    const int bb = bh >> 3, hh = bh & 7;
    const int lane = threadIdx.x & 63, wv = threadIdx.x >> 6;
    const int g = lane >> 4, li = lane & 15;
    const int q = qt * 64 + wv * 16 + li;          // this lane's q-row

    // Q fragments (B-operand: n = q = lane&15, k-slots = ks*32 + 8g + j)
    const size_t qoff = ((size_t)bh * SD_ + q) * DH + 8 * g;
    const s16x8 qh0 = *(const s16x8*)(Qh + qoff);
    const s16x8 qh1 = *(const s16x8*)(Qh + qoff + 32);
    const s16x8 ql0 = *(const s16x8*)(Ql + qoff);
    const s16x8 ql1 = *(const s16x8*)(Ql + qoff + 32);

    const unsigned short* __restrict__ Khb = Kh + (size_t)bh * SE_ * DH;
    const unsigned short* __restrict__ Klb = Kl + (size_t)bh * SE_ * DH;
    const unsigned short* __restrict__ Vtb = Vt + (size_t)bh * DH * SE_;
    const unsigned short* __restrict__ brow = Bias + (size_t)q * SE_;

    float m = -INFINITY, l = 0.f;
    f32x4 O[4];
#pragma unroll
    for (int i = 0; i < 4; ++i) O[i] = (f32x4){0.f, 0.f, 0.f, 0.f};

#pragma unroll 1
    for (int kt0 = 0; kt0 < SE_; kt0 += 64) {
        // ---- S^T accumulators init = bias (mask folded in; scale folded in Q) ----
        f32x4 s[4];
#pragma unroll
        for (int sub = 0; sub < 4; ++sub) {
            u16x4 bw = *(const u16x4*)(brow + kt0 + sub * 16 + 4 * g);
            s[sub][0] = bf2f(bw[0]); s[sub][1] = bf2f(bw[1]);
            s[sub][2] = bf2f(bw[2]); s[sub][3] = bf2f(bw[3]);
        }
        // ---- S^T += K Q^T (split bf16: KhQh + KhQl + KlQh) ----
#pragma unroll
        for (int sub = 0; sub < 4; ++sub) {
            const size_t kro = ((size_t)(kt0 + sub * 16 + li)) * DH + 8 * g;
            s16x8 kh0 = *(const s16x8*)(Khb + kro);
            s16x8 kh1 = *(const s16x8*)(Khb + kro + 32);
            s16x8 kl0 = *(const s16x8*)(Klb + kro);
            s16x8 kl1 = *(const s16x8*)(Klb + kro + 32);
            s[sub] = MFMA16(kh0, qh0, s[sub], 0, 0, 0);
            s[sub] = MFMA16(kh0, ql0, s[sub], 0, 0, 0);
            s[sub] = MFMA16(kl0, qh0, s[sub], 0, 0, 0);
            s[sub] = MFMA16(kh1, qh1, s[sub], 0, 0, 0);
            s[sub] = MFMA16(kh1, ql1, s[sub], 0, 0, 0);
            s[sub] = MFMA16(kl1, qh1, s[sub], 0, 0, 0);
        }

        // ---- online softmax for this lane's q (16 t-values in-lane, x4 groups) ----
        float tmax = fmaxf(fmaxf(s[0][0], s[0][1]), fmaxf(s[0][2], s[0][3]));
        tmax = fmaxf(tmax, fmaxf(fmaxf(s[1][0], s[1][1]), fmaxf(s[1][2], s[1][3])));
        tmax = fmaxf(tmax, fmaxf(fmaxf(s[2][0], s[2][1]), fmaxf(s[2][2], s[2][3])));
        tmax = fmaxf(tmax, fmaxf(fmaxf(s[3][0], s[3][1]), fmaxf(s[3][2], s[3][3])));
        tmax = fmaxf(tmax, __shfl_xor(tmax, 16));
        tmax = fmaxf(tmax, __shfl_xor(tmax, 32));
        const float mn  = fmaxf(m, tmax);
        const float scl = __expf(m - mn);          // exp(-inf)=0 on first tile
        float ps = 0.f;
#pragma unroll
        for (int sub = 0; sub < 4; ++sub)
#pragma unroll
            for (int c = 0; c < 4; ++c) {
                float p = __expf(s[sub][c] - mn);
                s[sub][c] = p;
                ps += p;
            }
        ps += __shfl_xor(ps, 16);
        ps += __shfl_xor(ps, 32);
        l = l * scl + ps;
        m = mn;
#pragma unroll
        for (int i = 0; i < 4; ++i) O[i] *= scl;

        // ---- pack P^T to bf16 frags (slot j=(sub&1)*4+r matches V sigma') ----
        s16x8 p0, p1;
        p0[0] = (short)f2bf(s[0][0]); p0[1] = (short)f2bf(s[0][1]);
        p0[2] = (short)f2bf(s[0][2]); p0[3] = (short)f2bf(s[0][3]);
        p0[4] = (short)f2bf(s[1][0]); p0[5] = (short)f2bf(s[1][1]);
        p0[6] = (short)f2bf(s[1][2]); p0[7] = (short)f2bf(s[1][3]);
        p1[0] = (short)f2bf(s[2][0]); p1[1] = (short)f2bf(s[2][1]);
        p1[2] = (short)f2bf(s[2][2]); p1[3] = (short)f2bf(s[2][3]);
        p1[4] = (short)f2bf(s[3][0]); p1[5] = (short)f2bf(s[3][1]);
        p1[6] = (short)f2bf(s[3][2]); p1[7] = (short)f2bf(s[3][3]);

        // ---- O^T += V^T P^T  (A = V^T from transposed storage, same sigma') ----
#pragma unroll
        for (int dsub = 0; dsub < 4; ++dsub) {
            const unsigned short* vp = Vtb + (size_t)(dsub * 16 + li) * SE_ + kt0 + 4 * g;
            s16x4 va = *(const s16x4*)(vp);
            s16x4 vb = *(const s16x4*)(vp + 16);
            s16x4 vc = *(const s16x4*)(vp + 32);
            s16x4 vd = *(const s16x4*)(vp + 48);
            s16x8 vf0 = __builtin_shufflevector(va, vb, 0, 1, 2, 3, 4, 5, 6, 7);
            s16x8 vf1 = __builtin_shufflevector(vc, vd, 0, 1, 2, 3, 4, 5, 6, 7);
            O[dsub] = MFMA16(vf0, p0, O[dsub], 0, 0, 0);
            O[dsub] = MFMA16(vf1, p1, O[dsub], 0, 0, 0);
        }
    }

    // ---- normalize + store AO[b][s][h][d]; lane's q = col, d = dsub*16+4g+reg
    const float rl = 1.f / l;
    float* __restrict__ aob = AO + (((size_t)bb * SD_ + q) * NH + hh) * DH;
#pragma unroll
    for (int dsub = 0; dsub < 4; ++dsub) {
        f32x4 o = O[dsub] * rl;
        *(f32x4*)(aob + dsub * 16 + 4 * g) = o;
    }
}

// ---------------------------------------------------------------------------
// Kernel 3: epilogue GEMM AO[8192,512] @ WO[512,300] -> out[8192,300].
// ---------------------------------------------------------------------------
__global__ __launch_bounds__(256) void epi_kernel(
    const float* __restrict__ AO, const float* __restrict__ WO,
    float* __restrict__ out)
{
    const int row0 = blockIdx.x * 64;
    const int c0   = blockIdx.y * 64;

    __shared__ float At[64][65];
    __shared__ float Bs[64][65];

    const int tid = threadIdx.x;
    const int tx = tid & 15, ty = tid >> 4;

    float acc[4][4];
#pragma unroll
    for (int i = 0; i < 4; ++i)
#pragma unroll
        for (int j = 0; j < 4; ++j) acc[i][j] = 0.f;

    for (int kc = 0; kc < HIDMID; kc += 64) {
        __syncthreads();
#pragma unroll
        for (int it = 0; it < 16; ++it) {
            int idx = tid + it * 256;
            int r  = idx >> 6;
            int kk = idx & 63;
            At[kk][r] = AO[(size_t)(row0 + r) * HIDMID + kc + kk];
            int kk2 = idx >> 6;
            int c   = idx & 63;
            int cg  = c0 + c;
            Bs[kk2][c] = (cg < HIDIN) ? WO[(size_t)(kc + kk2) * HIDIN + cg] : 0.f;
        }
        __syncthreads();
#pragma unroll 8
        for (int kk = 0; kk < 64; ++kk) {
            float a[4], b[4];
#pragma unroll
            for (int i = 0; i < 4; ++i) a[i] = At[kk][ty * 4 + i];
#pragma unroll
            for (int j = 0; j < 4; ++j) b[j] = Bs[kk][tx * 4 + j];
#pragma unroll
            for (int i = 0; i < 4; ++i)
#pragma unroll
                for (int j = 0; j < 4; ++j)
                    acc[i][j] = fmaf(a[i], b[j], acc[i][j]);
        }
    }

#pragma unroll
    for (int i = 0; i < 4; ++i) {
        int r = row0 + ty * 4 + i;
#pragma unroll
        for (int j = 0; j < 4; ++j) {
            int o = c0 + tx * 4 + j;
            if (o < HIDIN) out[(size_t)r * HIDIN + o] = acc[i][j];
        }
    }
}

// ---------------------------------------------------------------------------
extern "C" void kernel_launch(void* const* d_in, const int* in_sizes, int n_in,
                              void* d_out, int out_size, void* d_ws, size_t ws_size,
                              hipStream_t stream)
{
    const float* en  = (const float*)d_in[0];
    const float* de  = (const float*)d_in[1];
    const int*   mask = (const int*)d_in[2];
    const float* WQ  = (const float*)d_in[3];
    const float* WK  = (const float*)d_in[4];
    const float* WV  = (const float*)d_in[5];
    const float* WO  = (const float*)d_in[6];
    float* out = (float*)d_out;

    // ws layout (bf16 elems): Qh | Ql | Kh | Kl | Vt | Bias, then AO (f32)
    unsigned short* ws2 = (unsigned short*)d_ws;
    unsigned short* Qh   = ws2;
    unsigned short* Ql   = ws2 + ESZ;
    unsigned short* Kh   = ws2 + 2 * ESZ;
    unsigned short* Kl   = ws2 + 3 * ESZ;
    unsigned short* Vt   = ws2 + 4 * ESZ;
    unsigned short* Bias = ws2 + 5 * ESZ;
    float*          AO   = (float*)(ws2 + 6 * ESZ);

    bias_kernel<<<dim3(ESZ / 4 / 256), 256, 0, stream>>>(mask, Bias);
    proj_kernel<<<dim3(128, 8, 3), 256, 0, stream>>>(de, en, WQ, WK, WV,
                                                     Qh, Ql, Kh, Kl, Vt);
    attn_mfma_kernel<<<dim3(32, 32), 256, 0, stream>>>(Qh, Ql, Kh, Kl, Vt, Bias, AO);
    epi_kernel<<<dim3(128, 5), 256, 0, stream>>>(AO, WO, out);
}

// Round 4
// 649.771 us; speedup vs baseline: 1.4673x; 1.2056x over previous
//
#include <hip/hip_runtime.h>
#include <hip/hip_bf16.h>
#include <math.h>

#define B_      4
#define SD_     2048
#define SE_     2048
#define HIDIN   300
#define HIDMID  512
#define NH      8
#define DH      64
// elements per [32][2048][64] tensor (== 2048*2048)
#define ESZ     ((size_t)4194304)

typedef __attribute__((ext_vector_type(8))) short          s16x8;
typedef __attribute__((ext_vector_type(8))) unsigned short u16x8;
typedef __attribute__((ext_vector_type(4))) unsigned short u16x4;
typedef __attribute__((ext_vector_type(4))) float          f32x4;

#define MFMA16 __builtin_amdgcn_mfma_f32_16x16x32_bf16

__device__ __forceinline__ unsigned short f2bf(float f) {
    unsigned int u = __float_as_uint(f);
    u += 0x7fffu + ((u >> 16) & 1u);          // RNE
    return (unsigned short)(u >> 16);
}
__device__ __forceinline__ float bf2f(unsigned short s) {
    return __uint_as_float((unsigned int)s << 16);
}

// ---------------------------------------------------------------------------
// Kernel 0: mask (int32) -> additive bias bf16 {0,-1e9}, SWIZZLED layout:
// within each 64-t block: pos = gval*16 + sub*4 + c  (t = sub*16 + gval*4 + c)
// so a lane (group g) reads its 16 values as two contiguous 16B words.
// ---------------------------------------------------------------------------
__global__ __launch_bounds__(256) void bias_kernel(const int* __restrict__ mask,
                                                   unsigned short* __restrict__ Bias)
{
    const int i = blockIdx.x * 256 + threadIdx.x;    // 4 elems per thread
    const int4 mm = ((const int4*)mask)[i];
    const unsigned short NEG = f2bf(-1e9f);
    const int e0 = i * 4;
    const int q  = e0 >> 11;
    const int t0 = e0 & 2047;
    const size_t pos = (size_t)q * SE_ + (t0 & ~63) + ((t0 >> 2) & 3) * 16 + ((t0 >> 4) & 3) * 4;
    u16x4 o;
    o[0] = mm.x ? NEG : (unsigned short)0;
    o[1] = mm.y ? NEG : (unsigned short)0;
    o[2] = mm.z ? NEG : (unsigned short)0;
    o[3] = mm.w ? NEG : (unsigned short)0;
    *(u16x4*)(Bias + pos) = o;
}

// ---------------------------------------------------------------------------
// Kernel 1: fused QKV projection (fp32 math), outputs:
//   Q -> (scaled by 1/sqrt(300)) split bf16 Qh/Ql, layout [bh][s][d]
//   K -> split bf16 Kh/Kl, layout [bh][t][d]
//   V -> plain bf16 transposed+swizzled Vt[bh][d][swz(t)]
// swz(t) = (t&~31) | ((t>>2)&3)*8 | ((t>>4)&1)*4 | (t&3)
// ---------------------------------------------------------------------------
__global__ __launch_bounds__(256) void proj_kernel(
    const float* __restrict__ de, const float* __restrict__ en,
    const float* __restrict__ WQ, const float* __restrict__ WK,
    const float* __restrict__ WV,
    unsigned short* __restrict__ Qh, unsigned short* __restrict__ Ql,
    unsigned short* __restrict__ Kh, unsigned short* __restrict__ Kl,
    unsigned short* __restrict__ Vt)
{
    const int which = blockIdx.z;
    const float* __restrict__ A = (which == 0) ? de : en;
    const float* __restrict__ W = (which == 0) ? WQ : (which == 1 ? WK : WV);

    const int row0 = blockIdx.x * 64;
    const int c0   = blockIdx.y * 64;

    __shared__ float At[64][65];
    __shared__ float Bs[64][65];

    const int tid = threadIdx.x;
    const int tx = tid & 15, ty = tid >> 4;

    float acc[4][4];
#pragma unroll
    for (int i = 0; i < 4; ++i)
#pragma unroll
        for (int j = 0; j < 4; ++j) acc[i][j] = 0.f;

    for (int kc = 0; kc < HIDIN; kc += 64) {
        __syncthreads();
#pragma unroll
        for (int it = 0; it < 16; ++it) {
            int idx = tid + it * 256;
            int r  = idx >> 6;
            int kk = idx & 63;
            At[kk][r] = (kc + kk < HIDIN) ? A[(size_t)(row0 + r) * HIDIN + kc + kk] : 0.f;
            int kk2 = idx >> 6;
            int c   = idx & 63;
            Bs[kk2][c] = (kc + kk2 < HIDIN) ? W[(size_t)(kc + kk2) * HIDMID + c0 + c] : 0.f;
        }
        __syncthreads();
#pragma unroll 8
        for (int kk = 0; kk < 64; ++kk) {
            float a[4], b[4];
#pragma unroll
            for (int i = 0; i < 4; ++i) a[i] = At[kk][ty * 4 + i];
#pragma unroll
            for (int j = 0; j < 4; ++j) b[j] = Bs[kk][tx * 4 + j];
#pragma unroll
            for (int i = 0; i < 4; ++i)
#pragma unroll
                for (int j = 0; j < 4; ++j)
                    acc[i][j] = fmaf(a[i], b[j], acc[i][j]);
        }
    }

    const float scale = 0.057735026918962584f;  // 1/sqrt(300)
#pragma unroll
    for (int i = 0; i < 4; ++i) {
        int r  = row0 + ty * 4 + i;
        int bb = r >> 11;
        int s  = r & 2047;
#pragma unroll
        for (int j = 0; j < 4; ++j) {
            int jg = c0 + tx * 4 + j;
            int d  = jg >> 3;
            int hh = jg & 7;
            int bhn = bb * NH + hh;
            float val = acc[i][j];
            if (which == 0) {
                val *= scale;
                unsigned short hi = f2bf(val);
                unsigned short lo = f2bf(val - bf2f(hi));
                size_t o = ((size_t)bhn * SD_ + s) * DH + d;
                Qh[o] = hi; Ql[o] = lo;
            } else if (which == 1) {
                unsigned short hi = f2bf(val);
                unsigned short lo = f2bf(val - bf2f(hi));
                size_t o = ((size_t)bhn * SE_ + s) * DH + d;
                Kh[o] = hi; Kl[o] = lo;
            } else {
                int swz = (s & ~31) | (((s >> 2) & 3) << 3) | (((s >> 4) & 1) << 2) | (s & 3);
                Vt[((size_t)bhn * DH + d) * SE_ + swz] = f2bf(val);
            }
        }
    }
}

// ---------------------------------------------------------------------------
// Kernel 2: MFMA flash attention, explicitly software-pipelined.
// grid (32 q-tiles, 32 bh), block 256 = 4 independent waves. No LDS.
// Per iteration: [A] S-MFMAs from prefetched K/bias regs -> [B] issue K/bias
// loads for tile+1 -> [C] softmax (covers V latency) -> [D] PV MFMAs from
// prefetched V regs -> [E] issue V loads for tile+1.
// ---------------------------------------------------------------------------
__global__ __launch_bounds__(256) void attn_mfma_kernel(
    const unsigned short* __restrict__ Qh, const unsigned short* __restrict__ Ql,
    const unsigned short* __restrict__ Kh, const unsigned short* __restrict__ Kl,
    const unsigned short* __restrict__ Vt, const unsigned short* __restrict__ Bias,
    float* __restrict__ AO)
{
    const int qt = blockIdx.x, bh = blockIdx.y;
    const int bb = bh >> 3, hh = bh & 7;
    const int lane = threadIdx.x & 63, wv = threadIdx.x >> 6;
    const int g = lane >> 4, li = lane & 15;
    const int q = qt * 64 + wv * 16 + li;          // this lane's q-row

    // Q fragments (B-operand: n = q = lane&15, k-slots = ks*32 + 8g + j)
    const size_t qoff = ((size_t)bh * SD_ + q) * DH + 8 * g;
    const s16x8 qh0 = *(const s16x8*)(Qh + qoff);
    const s16x8 qh1 = *(const s16x8*)(Qh + qoff + 32);
    const s16x8 ql0 = *(const s16x8*)(Ql + qoff);
    const s16x8 ql1 = *(const s16x8*)(Ql + qoff + 32);

    const unsigned short* __restrict__ Khb = Kh + (size_t)bh * SE_ * DH + li * DH + 8 * g;
    const unsigned short* __restrict__ Klb = Kl + (size_t)bh * SE_ * DH + li * DH + 8 * g;
    const unsigned short* __restrict__ Vtb = Vt + (size_t)bh * DH * SE_ + (size_t)li * SE_ + 8 * g;
    const unsigned short* __restrict__ brow = Bias + (size_t)q * SE_ + 16 * g;

    float m = -INFINITY, l = 0.f;
    f32x4 O[4];
#pragma unroll
    for (int i = 0; i < 4; ++i) O[i] = (f32x4){0.f, 0.f, 0.f, 0.f};

    s16x8 kfr[4][4];   // [sub][kh0,kh1,kl0,kl1] for current tile
    u16x8 bfr[2];      // bias for current tile (swizzled 2x16B)
    s16x8 vfr[4][2];   // V frags for current tile

#define LOADK(kt)                                                             \
    _Pragma("unroll")                                                         \
    for (int sub = 0; sub < 4; ++sub) {                                       \
        const unsigned short* ph = Khb + (size_t)((kt) + sub * 16) * DH;      \
        const unsigned short* pl = Klb + (size_t)((kt) + sub * 16) * DH;      \
        kfr[sub][0] = *(const s16x8*)ph;                                      \
        kfr[sub][1] = *(const s16x8*)(ph + 32);                               \
        kfr[sub][2] = *(const s16x8*)pl;                                      \
        kfr[sub][3] = *(const s16x8*)(pl + 32);                               \
    }
#define LOADB(kt)                                                             \
    bfr[0] = *(const u16x8*)(brow + (kt));                                    \
    bfr[1] = *(const u16x8*)(brow + (kt) + 8);
#define LOADV(kt)                                                             \
    _Pragma("unroll")                                                         \
    for (int dsub = 0; dsub < 4; ++dsub) {                                    \
        const unsigned short* vp = Vtb + (size_t)(dsub * 16) * SE_ + (kt);    \
        vfr[dsub][0] = *(const s16x8*)vp;                                     \
        vfr[dsub][1] = *(const s16x8*)(vp + 32);                              \
    }

    LOADK(0)
    LOADB(0)
    LOADV(0)

#pragma unroll 1
    for (int kt0 = 0; kt0 < SE_; kt0 += 64) {
        // ---- [A] S^T acc init from bias regs; S-MFMAs consume kfr ----
        f32x4 s[4];
#pragma unroll
        for (int sub = 0; sub < 4; ++sub)
#pragma unroll
            for (int c = 0; c < 4; ++c)
                s[sub][c] = bf2f(bfr[sub >> 1][(sub & 1) * 4 + c]);
#pragma unroll
        for (int sub = 0; sub < 4; ++sub) {
            s[sub] = MFMA16(kfr[sub][0], qh0, s[sub], 0, 0, 0);
            s[sub] = MFMA16(kfr[sub][0], ql0, s[sub], 0, 0, 0);
            s[sub] = MFMA16(kfr[sub][2], qh0, s[sub], 0, 0, 0);
            s[sub] = MFMA16(kfr[sub][1], qh1, s[sub], 0, 0, 0);
            s[sub] = MFMA16(kfr[sub][1], ql1, s[sub], 0, 0, 0);
            s[sub] = MFMA16(kfr[sub][3], qh1, s[sub], 0, 0, 0);
        }

        // ---- [B] prefetch next tile's K and bias (kfr/bfr now dead) ----
        const int ktn = (kt0 + 64) & (SE_ - 1);
        LOADK(ktn)
        LOADB(ktn)

        // ---- [C] online softmax (lane's q fixed; 16 t-values across g-groups)
        float tmax = fmaxf(fmaxf(s[0][0], s[0][1]), fmaxf(s[0][2], s[0][3]));
        tmax = fmaxf(tmax, fmaxf(fmaxf(s[1][0], s[1][1]), fmaxf(s[1][2], s[1][3])));
        tmax = fmaxf(tmax, fmaxf(fmaxf(s[2][0], s[2][1]), fmaxf(s[2][2], s[2][3])));
        tmax = fmaxf(tmax, fmaxf(fmaxf(s[3][0], s[3][1]), fmaxf(s[3][2], s[3][3])));
        tmax = fmaxf(tmax, __shfl_xor(tmax, 16));
        tmax = fmaxf(tmax, __shfl_xor(tmax, 32));
        const float mn  = fmaxf(m, tmax);
        const float scl = __expf(m - mn);          // exp(-inf)=0 on first tile
        float ps = 0.f;
#pragma unroll
        for (int sub = 0; sub < 4; ++sub)
#pragma unroll
            for (int c = 0; c < 4; ++c) {
                float p = __expf(s[sub][c] - mn);
                s[sub][c] = p;
                ps += p;
            }
        ps += __shfl_xor(ps, 16);
        ps += __shfl_xor(ps, 32);
        l = l * scl + ps;
        m = mn;
#pragma unroll
        for (int i = 0; i < 4; ++i) O[i] *= scl;

        // ---- [D] pack P -> bf16 (v_cvt_pk), PV MFMAs consume vfr ----
        union { s16x8 v; unsigned int w[4]; } P0, P1;
        asm("v_cvt_pk_bf16_f32 %0, %1, %2" : "=v"(P0.w[0]) : "v"(s[0][0]), "v"(s[0][1]));
        asm("v_cvt_pk_bf16_f32 %0, %1, %2" : "=v"(P0.w[1]) : "v"(s[0][2]), "v"(s[0][3]));
        asm("v_cvt_pk_bf16_f32 %0, %1, %2" : "=v"(P0.w[2]) : "v"(s[1][0]), "v"(s[1][1]));
        asm("v_cvt_pk_bf16_f32 %0, %1, %2" : "=v"(P0.w[3]) : "v"(s[1][2]), "v"(s[1][3]));
        asm("v_cvt_pk_bf16_f32 %0, %1, %2" : "=v"(P1.w[0]) : "v"(s[2][0]), "v"(s[2][1]));
        asm("v_cvt_pk_bf16_f32 %0, %1, %2" : "=v"(P1.w[1]) : "v"(s[2][2]), "v"(s[2][3]));
        asm("v_cvt_pk_bf16_f32 %0, %1, %2" : "=v"(P1.w[2]) : "v"(s[3][0]), "v"(s[3][1]));
        asm("v_cvt_pk_bf16_f32 %0, %1, %2" : "=v"(P1.w[3]) : "v"(s[3][2]), "v"(s[3][3]));

#pragma unroll
        for (int dsub = 0; dsub < 4; ++dsub) {
            O[dsub] = MFMA16(vfr[dsub][0], P0.v, O[dsub], 0, 0, 0);
            O[dsub] = MFMA16(vfr[dsub][1], P1.v, O[dsub], 0, 0, 0);
        }

        // ---- [E] prefetch next tile's V (vfr now dead) ----
        LOADV(ktn)
    }

    // ---- normalize + store AO[b][s][h][d]; d = dsub*16 + 4g + reg ----
    const float rl = 1.f / l;
    float* __restrict__ aob = AO + (((size_t)bb * SD_ + q) * NH + hh) * DH;
#pragma unroll
    for (int dsub = 0; dsub < 4; ++dsub) {
        f32x4 o = O[dsub] * rl;
        *(f32x4*)(aob + dsub * 16 + 4 * g) = o;
    }
#undef LOADK
#undef LOADB
#undef LOADV
}

// ---------------------------------------------------------------------------
// Kernel 3: epilogue GEMM AO[8192,512] @ WO[512,300] -> out[8192,300].
// ---------------------------------------------------------------------------
__global__ __launch_bounds__(256) void epi_kernel(
    const float* __restrict__ AO, const float* __restrict__ WO,
    float* __restrict__ out)
{
    const int row0 = blockIdx.x * 64;
    const int c0   = blockIdx.y * 64;

    __shared__ float At[64][65];
    __shared__ float Bs[64][65];

    const int tid = threadIdx.x;
    const int tx = tid & 15, ty = tid >> 4;

    float acc[4][4];
#pragma unroll
    for (int i = 0; i < 4; ++i)
#pragma unroll
        for (int j = 0; j < 4; ++j) acc[i][j] = 0.f;

    for (int kc = 0; kc < HIDMID; kc += 64) {
        __syncthreads();
#pragma unroll
        for (int it = 0; it < 16; ++it) {
            int idx = tid + it * 256;
            int r  = idx >> 6;
            int kk = idx & 63;
            At[kk][r] = AO[(size_t)(row0 + r) * HIDMID + kc + kk];
            int kk2 = idx >> 6;
            int c   = idx & 63;
            int cg  = c0 + c;
            Bs[kk2][c] = (cg < HIDIN) ? WO[(size_t)(kc + kk2) * HIDIN + cg] : 0.f;
        }
        __syncthreads();
#pragma unroll 8
        for (int kk = 0; kk < 64; ++kk) {
            float a[4], b[4];
#pragma unroll
            for (int i = 0; i < 4; ++i) a[i] = At[kk][ty * 4 + i];
#pragma unroll
            for (int j = 0; j < 4; ++j) b[j] = Bs[kk][tx * 4 + j];
#pragma unroll
            for (int i = 0; i < 4; ++i)
#pragma unroll
                for (int j = 0; j < 4; ++j)
                    acc[i][j] = fmaf(a[i], b[j], acc[i][j]);
        }
    }

#pragma unroll
    for (int i = 0; i < 4; ++i) {
        int r = row0 + ty * 4 + i;
#pragma unroll
        for (int j = 0; j < 4; ++j) {
            int o = c0 + tx * 4 + j;
            if (o < HIDIN) out[(size_t)r * HIDIN + o] = acc[i][j];
        }
    }
}

// ---------------------------------------------------------------------------
extern "C" void kernel_launch(void* const* d_in, const int* in_sizes, int n_in,
                              void* d_out, int out_size, void* d_ws, size_t ws_size,
                              hipStream_t stream)
{
    const float* en  = (const float*)d_in[0];
    const float* de  = (const float*)d_in[1];
    const int*   mask = (const int*)d_in[2];
    const float* WQ  = (const float*)d_in[3];
    const float* WK  = (const float*)d_in[4];
    const float* WV  = (const float*)d_in[5];
    const float* WO  = (const float*)d_in[6];
    float* out = (float*)d_out;

    // ws layout (bf16 elems): Qh | Ql | Kh | Kl | Vt | Bias, then AO (f32)
    unsigned short* ws2 = (unsigned short*)d_ws;
    unsigned short* Qh   = ws2;
    unsigned short* Ql   = ws2 + ESZ;
    unsigned short* Kh   = ws2 + 2 * ESZ;
    unsigned short* Kl   = ws2 + 3 * ESZ;
    unsigned short* Vt   = ws2 + 4 * ESZ;
    unsigned short* Bias = ws2 + 5 * ESZ;
    float*          AO   = (float*)(ws2 + 6 * ESZ);

    bias_kernel<<<dim3(ESZ / 4 / 256), 256, 0, stream>>>(mask, Bias);
    proj_kernel<<<dim3(128, 8, 3), 256, 0, stream>>>(de, en, WQ, WK, WV,
                                                     Qh, Ql, Kh, Kl, Vt);
    attn_mfma_kernel<<<dim3(32, 32), 256, 0, stream>>>(Qh, Ql, Kh, Kl, Vt, Bias, AO);
    epi_kernel<<<dim3(128, 5), 256, 0, stream>>>(AO, WO, out);
}

// Round 5
// 377.887 us; speedup vs baseline: 2.5229x; 1.7195x over previous
//
#include <hip/hip_runtime.h>
#include <hip/hip_bf16.h>
#include <math.h>

#define B_      4
#define SD_     2048
#define SE_     2048
#define HIDIN   300
#define HIDMID  512
#define NH      8
#define DH      64
#define ESZ     ((size_t)4194304)          // elems per [32][2048][64] tensor
#define TILEU   4096                        // ushorts per 64x64 bf16 tile
#define BUFB    24576                       // bytes per LDS buffer (Kh+Kl+V)

typedef __attribute__((ext_vector_type(8))) short          s16x8;
typedef __attribute__((ext_vector_type(4))) float          f32x4;

#define MFMA16 __builtin_amdgcn_mfma_f32_16x16x32_bf16

// logit scale: (1/sqrt(300)) * log2(e)  -> softmax done in base-2 (exact same result)
#define QSCALE  0.0832940411f
#define NEGL   -1.4426950e9f               // -1e9 * log2e (masked logit, base-2 units)

__device__ __forceinline__ unsigned short f2bf(float f) {
    unsigned int u = __float_as_uint(f);
    u += 0x7fffu + ((u >> 16) & 1u);          // RNE
    return (unsigned short)(u >> 16);
}
__device__ __forceinline__ float bf2f(unsigned short s) {
    return __uint_as_float((unsigned int)s << 16);
}

__device__ __forceinline__ void gload16(const void* g, void* l) {
    __builtin_amdgcn_global_load_lds(
        (const __attribute__((address_space(1))) void*)g,
        (__attribute__((address_space(3))) void*)l, 16, 0, 0);
}

// ---------------------------------------------------------------------------
// Kernel 0: mask (int32) -> packed bits. One u64 per (q, 64-t tile):
// bit position = g*16 + sub*4 + c for t_in = sub*16 + g*4 + c.
// ---------------------------------------------------------------------------
__global__ __launch_bounds__(256) void bias_kernel(const int* __restrict__ mask,
                                                   unsigned long long* __restrict__ BiasB)
{
    const int idx = blockIdx.x * 256 + threadIdx.x;    // 65536 threads
    const int q = idx >> 5, tile = idx & 31;
    const int* __restrict__ mrow = mask + (size_t)q * SE_ + tile * 64;
    unsigned long long w = 0;
#pragma unroll
    for (int sub = 0; sub < 4; ++sub)
#pragma unroll
        for (int gv = 0; gv < 4; ++gv) {
            const int4 mm = *(const int4*)(mrow + sub * 16 + gv * 4);
            const int bp = gv * 16 + sub * 4;
            if (mm.x) w |= 1ull << bp;
            if (mm.y) w |= 1ull << (bp + 1);
            if (mm.z) w |= 1ull << (bp + 2);
            if (mm.w) w |= 1ull << (bp + 3);
        }
    BiasB[idx] = w;
}

// ---------------------------------------------------------------------------
// Kernel 1: fused QKV projection (fp32 math).
//   Q -> (scaled by QSCALE) split bf16 Qh/Ql, layout [bh][s][d]
//   K -> split bf16 KhT/KlT in TILED+SWIZZLED layout [bh][tile][t(64)][swz-chunk d]
//        chunk' = (d>>3) ^ (t&7)
//   V -> bf16 TILED+SWIZZLED transposed [bh][tile][d(64)][swz t-order]
//        within row d: elem order p = (chunk' = (blk*4+gg)^(d&7))*8 + half*4 + c
//        for t_in = blk*32 + half*16 + gg*4 + c
// ---------------------------------------------------------------------------
__global__ __launch_bounds__(256) void proj_kernel(
    const float* __restrict__ de, const float* __restrict__ en,
    const float* __restrict__ WQ, const float* __restrict__ WK,
    const float* __restrict__ WV,
    unsigned short* __restrict__ Qh, unsigned short* __restrict__ Ql,
    unsigned short* __restrict__ KhT, unsigned short* __restrict__ KlT,
    unsigned short* __restrict__ VtT)
{
    const int which = blockIdx.z;
    const float* __restrict__ A = (which == 0) ? de : en;
    const float* __restrict__ W = (which == 0) ? WQ : (which == 1 ? WK : WV);

    const int row0 = blockIdx.x * 64;
    const int c0   = blockIdx.y * 64;

    __shared__ float At[64][65];
    __shared__ float Bs[64][65];

    const int tid = threadIdx.x;
    const int tx = tid & 15, ty = tid >> 4;

    float acc[4][4];
#pragma unroll
    for (int i = 0; i < 4; ++i)
#pragma unroll
        for (int j = 0; j < 4; ++j) acc[i][j] = 0.f;

    for (int kc = 0; kc < HIDIN; kc += 64) {
        __syncthreads();
#pragma unroll
        for (int it = 0; it < 16; ++it) {
            int idx = tid + it * 256;
            int r  = idx >> 6;
            int kk = idx & 63;
            At[kk][r] = (kc + kk < HIDIN) ? A[(size_t)(row0 + r) * HIDIN + kc + kk] : 0.f;
            int kk2 = idx >> 6;
            int c   = idx & 63;
            Bs[kk2][c] = (kc + kk2 < HIDIN) ? W[(size_t)(kc + kk2) * HIDMID + c0 + c] : 0.f;
        }
        __syncthreads();
#pragma unroll 8
        for (int kk = 0; kk < 64; ++kk) {
            float a[4], b[4];
#pragma unroll
            for (int i = 0; i < 4; ++i) a[i] = At[kk][ty * 4 + i];
#pragma unroll
            for (int j = 0; j < 4; ++j) b[j] = Bs[kk][tx * 4 + j];
#pragma unroll
            for (int i = 0; i < 4; ++i)
#pragma unroll
                for (int j = 0; j < 4; ++j)
                    acc[i][j] = fmaf(a[i], b[j], acc[i][j]);
        }
    }

#pragma unroll
    for (int i = 0; i < 4; ++i) {
        int r  = row0 + ty * 4 + i;
        int bb = r >> 11;
        int s  = r & 2047;
#pragma unroll
        for (int j = 0; j < 4; ++j) {
            int jg = c0 + tx * 4 + j;
            int d  = jg >> 3;
            int hh = jg & 7;
            int bhn = bb * NH + hh;
            float val = acc[i][j];
            const int tile = s >> 6;
            const size_t tbase = (((size_t)bhn * 32 + tile) << 12);
            if (which == 0) {
                val *= QSCALE;
                unsigned short hi = f2bf(val);
                unsigned short lo = f2bf(val - bf2f(hi));
                size_t o = ((size_t)bhn * SD_ + s) * DH + d;
                Qh[o] = hi; Ql[o] = lo;
            } else if (which == 1) {
                unsigned short hi = f2bf(val);
                unsigned short lo = f2bf(val - bf2f(hi));
                const int tt = s & 63;
                size_t o = tbase + tt * 64 + (((d >> 3) ^ (tt & 7)) << 3) + (d & 7);
                KhT[o] = hi; KlT[o] = lo;
            } else {
                const int tin = s & 63;
                const int blk = tin >> 5, gg = (tin >> 2) & 3;
                const int half = (tin >> 4) & 1, cc = tin & 3;
                size_t o = tbase + d * 64 + ((((blk << 2) | gg) ^ (d & 7)) << 3)
                         + half * 4 + cc;
                VtT[o] = f2bf(val);
            }
        }
    }
}

// ---------------------------------------------------------------------------
// Kernel 2: MFMA flash attention, LDS-staged double-buffered.
// grid (16 q-tiles of 128, 32 bh), block 512 = 8 waves sharing K/Kl/V tiles.
// Per iter: stage(next tile -> other buf, fire-and-forget) ; compute current
// from LDS ; __syncthreads (drains vmcnt + barrier) ; swap.
// ---------------------------------------------------------------------------
__global__ __launch_bounds__(512, 4) void attn_mfma_kernel(
    const unsigned short* __restrict__ Qh, const unsigned short* __restrict__ Ql,
    const unsigned short* __restrict__ KhT, const unsigned short* __restrict__ KlT,
    const unsigned short* __restrict__ VtT, const unsigned short* __restrict__ BiasP,
    float* __restrict__ AO)
{
    const int qt = blockIdx.x, bh = blockIdx.y;
    const int bb = bh >> 3, hh = bh & 7;
    const int tid = threadIdx.x;
    const int wv = tid >> 6, lane = tid & 63;
    const int g = lane >> 4, li = lane & 15;
    const int q = qt * 128 + wv * 16 + li;

    __shared__ __align__(16) char LB[2 * BUFB];

    // ---- Q fragments (registers, persistent) ----
    const size_t qoff = ((size_t)bh * SD_ + q) * DH + 8 * g;
    const s16x8 qh0 = *(const s16x8*)(Qh + qoff);
    const s16x8 qh1 = *(const s16x8*)(Qh + qoff + 32);
    const s16x8 ql0 = *(const s16x8*)(Ql + qoff);
    const s16x8 ql1 = *(const s16x8*)(Ql + qoff + 32);

    // ---- staging source bases (ushort ptrs, per-thread 16B chunk) ----
    const unsigned short* __restrict__ sKh = KhT + ((size_t)bh << 17) + tid * 8;
    const unsigned short* __restrict__ sKl = KlT + ((size_t)bh << 17) + tid * 8;
    const unsigned short* __restrict__ sVt = VtT + ((size_t)bh << 17) + tid * 8;

    // ---- per-lane LDS read bases (byte offsets; chunk-XOR swizzle) ----
    const int base0 = li * 128 + ((g ^ (li & 7)) << 4);
    const int base1 = li * 128 + (((4 + g) ^ (li & 7)) << 4);

#define STAGE(tile, boff)                                                     \
    {                                                                         \
        char* db = LB + (boff) + wv * 1024;                                   \
        const size_t toff = (size_t)(tile) << 12;                             \
        gload16(sKh + toff, db);                                              \
        gload16(sKl + toff, db + 8192);                                       \
        gload16(sVt + toff, db + 16384);                                      \
    }

    float m = -INFINITY, l = 0.f;
    f32x4 O[4];
#pragma unroll
    for (int i = 0; i < 4; ++i) O[i] = (f32x4){0.f, 0.f, 0.f, 0.f};

    // prologue: stage tile 0 into buf 0
    STAGE(0, 0)
    unsigned short bw = BiasP[(size_t)q * 128 + g];
    __syncthreads();

    int bufoff = 0;
#pragma unroll 1
    for (int it = 0; it < 32; ++it) {
        const int nxt = (it + 1) & 31;
        // ---- stage next tile into the other buffer (async, fire-and-forget)
        STAGE(nxt, bufoff ^ BUFB)
        const unsigned short bwN = BiasP[(size_t)q * 128 + nxt * 4 + g];

        // ---- acc init from mask bits (bit sub*4+c of this lane's ushort) ----
        f32x4 s[4];
#pragma unroll
        for (int sub = 0; sub < 4; ++sub)
#pragma unroll
            for (int c = 0; c < 4; ++c)
                s[sub][c] = ((bw >> (sub * 4 + c)) & 1) ? NEGL : 0.f;

        // ---- S^T += K Q^T from LDS (split bf16, 6 MFMAs per 16-t sub) ----
#pragma unroll
        for (int sub = 0; sub < 4; ++sub) {
            const s16x8 kh0 = *(const s16x8*)(LB + bufoff + base0 + sub * 2048);
            const s16x8 kh1 = *(const s16x8*)(LB + bufoff + base1 + sub * 2048);
            const s16x8 kl0 = *(const s16x8*)(LB + bufoff + base0 + 8192 + sub * 2048);
            const s16x8 kl1 = *(const s16x8*)(LB + bufoff + base1 + 8192 + sub * 2048);
            s[sub] = MFMA16(kh0, qh0, s[sub], 0, 0, 0);
            s[sub] = MFMA16(kh0, ql0, s[sub], 0, 0, 0);
            s[sub] = MFMA16(kl0, qh0, s[sub], 0, 0, 0);
            s[sub] = MFMA16(kh1, qh1, s[sub], 0, 0, 0);
            s[sub] = MFMA16(kh1, ql1, s[sub], 0, 0, 0);
            s[sub] = MFMA16(kl1, qh1, s[sub], 0, 0, 0);
        }

        // ---- online softmax in base-2 (lane's q fixed; 16 t across g-groups)
        float tmax = fmaxf(fmaxf(s[0][0], s[0][1]), fmaxf(s[0][2], s[0][3]));
        tmax = fmaxf(tmax, fmaxf(fmaxf(s[1][0], s[1][1]), fmaxf(s[1][2], s[1][3])));
        tmax = fmaxf(tmax, fmaxf(fmaxf(s[2][0], s[2][1]), fmaxf(s[2][2], s[2][3])));
        tmax = fmaxf(tmax, fmaxf(fmaxf(s[3][0], s[3][1]), fmaxf(s[3][2], s[3][3])));
        tmax = fmaxf(tmax, __shfl_xor(tmax, 16));
        tmax = fmaxf(tmax, __shfl_xor(tmax, 32));
        const float mn  = fmaxf(m, tmax);
        const float scl = exp2f(m - mn);           // exp2(-inf)=0 on first tile
        float ps = 0.f;
#pragma unroll
        for (int sub = 0; sub < 4; ++sub)
#pragma unroll
            for (int c = 0; c < 4; ++c) {
                float p = exp2f(s[sub][c] - mn);
                s[sub][c] = p;
                ps += p;
            }
        ps += __shfl_xor(ps, 16);
        ps += __shfl_xor(ps, 32);
        l = l * scl + ps;
        m = mn;
#pragma unroll
        for (int i = 0; i < 4; ++i) O[i] *= scl;

        // ---- pack P -> bf16 (slots match V sigma') ----
        union { s16x8 v; unsigned int w[4]; } P0, P1;
        asm("v_cvt_pk_bf16_f32 %0, %1, %2" : "=v"(P0.w[0]) : "v"(s[0][0]), "v"(s[0][1]));
        asm("v_cvt_pk_bf16_f32 %0, %1, %2" : "=v"(P0.w[1]) : "v"(s[0][2]), "v"(s[0][3]));
        asm("v_cvt_pk_bf16_f32 %0, %1, %2" : "=v"(P0.w[2]) : "v"(s[1][0]), "v"(s[1][1]));
        asm("v_cvt_pk_bf16_f32 %0, %1, %2" : "=v"(P0.w[3]) : "v"(s[1][2]), "v"(s[1][3]));
        asm("v_cvt_pk_bf16_f32 %0, %1, %2" : "=v"(P1.w[0]) : "v"(s[2][0]), "v"(s[2][1]));
        asm("v_cvt_pk_bf16_f32 %0, %1, %2" : "=v"(P1.w[1]) : "v"(s[2][2]), "v"(s[2][3]));
        asm("v_cvt_pk_bf16_f32 %0, %1, %2" : "=v"(P1.w[2]) : "v"(s[3][0]), "v"(s[3][1]));
        asm("v_cvt_pk_bf16_f32 %0, %1, %2" : "=v"(P1.w[3]) : "v"(s[3][2]), "v"(s[3][3]));

        // ---- O^T += V^T P^T from LDS ----
#pragma unroll
        for (int dsub = 0; dsub < 4; ++dsub) {
            const s16x8 vf0 = *(const s16x8*)(LB + bufoff + base0 + 16384 + dsub * 2048);
            const s16x8 vf1 = *(const s16x8*)(LB + bufoff + base1 + 16384 + dsub * 2048);
            O[dsub] = MFMA16(vf0, P0.v, O[dsub], 0, 0, 0);
            O[dsub] = MFMA16(vf1, P1.v, O[dsub], 0, 0, 0);
        }

        bw = bwN;
        __syncthreads();          // drains vmcnt (staging landed) + barrier
        bufoff ^= BUFB;
    }

    // ---- normalize + store AO[b][s][h][d]; d = dsub*16 + 4g + reg ----
    const float rl = 1.f / l;
    float* __restrict__ aob = AO + (((size_t)bb * SD_ + q) * NH + hh) * DH;
#pragma unroll
    for (int dsub = 0; dsub < 4; ++dsub) {
        f32x4 o = O[dsub] * rl;
        *(f32x4*)(aob + dsub * 16 + 4 * g) = o;
    }
#undef STAGE
}

// ---------------------------------------------------------------------------
// Kernel 3: epilogue GEMM AO[8192,512] @ WO[512,300] -> out[8192,300].
// ---------------------------------------------------------------------------
__global__ __launch_bounds__(256) void epi_kernel(
    const float* __restrict__ AO, const float* __restrict__ WO,
    float* __restrict__ out)
{
    const int row0 = blockIdx.x * 64;
    const int c0   = blockIdx.y * 64;

    __shared__ float At[64][65];
    __shared__ float Bs[64][65];

    const int tid = threadIdx.x;
    const int tx = tid & 15, ty = tid >> 4;

    float acc[4][4];
#pragma unroll
    for (int i = 0; i < 4; ++i)
#pragma unroll
        for (int j = 0; j < 4; ++j) acc[i][j] = 0.f;

    for (int kc = 0; kc < HIDMID; kc += 64) {
        __syncthreads();
#pragma unroll
        for (int it = 0; it < 16; ++it) {
            int idx = tid + it * 256;
            int r  = idx >> 6;
            int kk = idx & 63;
            At[kk][r] = AO[(size_t)(row0 + r) * HIDMID + kc + kk];
            int kk2 = idx >> 6;
            int c   = idx & 63;
            int cg  = c0 + c;
            Bs[kk2][c] = (cg < HIDIN) ? WO[(size_t)(kc + kk2) * HIDIN + cg] : 0.f;
        }
        __syncthreads();
#pragma unroll 8
        for (int kk = 0; kk < 64; ++kk) {
            float a[4], b[4];
#pragma unroll
            for (int i = 0; i < 4; ++i) a[i] = At[kk][ty * 4 + i];
#pragma unroll
            for (int j = 0; j < 4; ++j) b[j] = Bs[kk][tx * 4 + j];
#pragma unroll
            for (int i = 0; i < 4; ++i)
#pragma unroll
                for (int j = 0; j < 4; ++j)
                    acc[i][j] = fmaf(a[i], b[j], acc[i][j]);
        }
    }

#pragma unroll
    for (int i = 0; i < 4; ++i) {
        int r = row0 + ty * 4 + i;
#pragma unroll
        for (int j = 0; j < 4; ++j) {
            int o = c0 + tx * 4 + j;
            if (o < HIDIN) out[(size_t)r * HIDIN + o] = acc[i][j];
        }
    }
}

// ---------------------------------------------------------------------------
extern "C" void kernel_launch(void* const* d_in, const int* in_sizes, int n_in,
                              void* d_out, int out_size, void* d_ws, size_t ws_size,
                              hipStream_t stream)
{
    const float* en  = (const float*)d_in[0];
    const float* de  = (const float*)d_in[1];
    const int*   mask = (const int*)d_in[2];
    const float* WQ  = (const float*)d_in[3];
    const float* WK  = (const float*)d_in[4];
    const float* WV  = (const float*)d_in[5];
    const float* WO  = (const float*)d_in[6];
    float* out = (float*)d_out;

    // ws layout (ushort elems): Qh | Ql | KhT | KlT | VtT | BiasBits(u64 x65536) | AO(f32)
    unsigned short* ws2 = (unsigned short*)d_ws;
    unsigned short* Qh   = ws2;
    unsigned short* Ql   = ws2 + ESZ;
    unsigned short* KhT  = ws2 + 2 * ESZ;
    unsigned short* KlT  = ws2 + 3 * ESZ;
    unsigned short* VtT  = ws2 + 4 * ESZ;
    unsigned long long* BiasB = (unsigned long long*)(ws2 + 5 * ESZ);
    float*          AO   = (float*)(ws2 + 5 * ESZ + 262144);   // 65536 u64 = 262144 ushorts

    bias_kernel<<<dim3(256), 256, 0, stream>>>(mask, BiasB);
    proj_kernel<<<dim3(128, 8, 3), 256, 0, stream>>>(de, en, WQ, WK, WV,
                                                     Qh, Ql, KhT, KlT, VtT);
    attn_mfma_kernel<<<dim3(16, 32), 512, 0, stream>>>(Qh, Ql, KhT, KlT, VtT,
                                                       (const unsigned short*)BiasB, AO);
    epi_kernel<<<dim3(128, 5), 256, 0, stream>>>(AO, WO, out);
}

// Round 6
// 192.102 us; speedup vs baseline: 4.9629x; 1.9671x over previous
//
#include <hip/hip_runtime.h>
#include <hip/hip_bf16.h>
#include <math.h>

#define B_      4
#define SD_     2048
#define SE_     2048
#define HIDIN   300
#define HIDMID  512
#define NH      8
#define DH      64
#define ESZ     ((size_t)4194304)          // elems per [32][2048][64] tensor
#define BUFB    24576                       // bytes per attn LDS buffer (Kh+Kl+V)

typedef __attribute__((ext_vector_type(8))) short          s16x8;
typedef __attribute__((ext_vector_type(8))) unsigned short u16x8;
typedef __attribute__((ext_vector_type(4))) unsigned short u16x4;
typedef __attribute__((ext_vector_type(4))) float          f32x4;

#define MFMA16 __builtin_amdgcn_mfma_f32_16x16x32_bf16

// logit scale: (1/sqrt(300)) * log2(e)  -> softmax done in base-2
#define QSCALE  0.0832940411f
#define NEGL   -1.4426950e9f               // -1e9 * log2e

__device__ __forceinline__ unsigned short f2bf(float f) {
    unsigned int u = __float_as_uint(f);
    u += 0x7fffu + ((u >> 16) & 1u);          // RNE
    return (unsigned short)(u >> 16);
}
__device__ __forceinline__ float bf2f(unsigned short s) {
    return __uint_as_float((unsigned int)s << 16);
}
__device__ __forceinline__ void gload16(const void* g, void* l) {
    __builtin_amdgcn_global_load_lds(
        (const __attribute__((address_space(1))) void*)g,
        (__attribute__((address_space(3))) void*)l, 16, 0, 0);
}

// ws ushort offsets
#define OF_QH   ((size_t)0)
#define OF_QL   (ESZ)
#define OF_KH   (2*ESZ)
#define OF_KL   (3*ESZ)
#define OF_VT   (4*ESZ)
#define OF_BB   (5*ESZ)                    // 262144 ushorts of bias bits
#define OF_CA   (5*ESZ + 262144)           // deH,deL,enH,enL (4 x 2621440)
#define OF_CW   (OF_CA + 10485760)         // WQh,WQl,WKh,WKl,WVh,WVl (6 x 163840)
#define OF_WOT  (OF_CW + 983040)           // 196608

// ---------------------------------------------------------------------------
// Kernel 0: mask (int32) -> packed bits. One u64 per (q, 64-t tile).
// ---------------------------------------------------------------------------
__global__ __launch_bounds__(256) void bias_kernel(const int* __restrict__ mask,
                                                   unsigned long long* __restrict__ BiasB)
{
    const int idx = blockIdx.x * 256 + threadIdx.x;    // 65536 threads
    const int q = idx >> 5, tile = idx & 31;
    const int* __restrict__ mrow = mask + (size_t)q * SE_ + tile * 64;
    unsigned long long w = 0;
#pragma unroll
    for (int sub = 0; sub < 4; ++sub)
#pragma unroll
        for (int gv = 0; gv < 4; ++gv) {
            const int4 mm = *(const int4*)(mrow + sub * 16 + gv * 4);
            const int bp = gv * 16 + sub * 4;
            if (mm.x) w |= 1ull << bp;
            if (mm.y) w |= 1ull << (bp + 1);
            if (mm.z) w |= 1ull << (bp + 2);
            if (mm.w) w |= 1ull << (bp + 3);
        }
    BiasB[idx] = w;
}

// ---------------------------------------------------------------------------
// Kernel 1a: de/en fp32 -> split bf16 hi/lo, tiled GEMM-A layout:
// T[((row>>7)*10 + ch)*4096 + (row&127)*32 + ((kk>>3)^(((row&127)>>1)&3))*8 + (kk&7)]
// K padded 300 -> 320 (10 chunks of 32).
// ---------------------------------------------------------------------------
__global__ __launch_bounds__(256) void convA_kernel(
    const float* __restrict__ de, const float* __restrict__ en,
    unsigned short* __restrict__ CA)
{
    const int idx = blockIdx.x * 256 + threadIdx.x;    // 81920 per matrix
    const int mat = blockIdx.y;
    const float* __restrict__ A = mat ? en : de;
    unsigned short* __restrict__ H = CA + (size_t)mat * 5242880;
    unsigned short* __restrict__ L = H + 2621440;
    const int row = idx / 10, ch = idx - row * 10;
    float v[32];
    if (ch < 9) {
#pragma unroll
        for (int i = 0; i < 8; ++i) {
            const float4 f = *(const float4*)(A + (size_t)row * 300 + ch * 32 + i * 4);
            v[i*4+0] = f.x; v[i*4+1] = f.y; v[i*4+2] = f.z; v[i*4+3] = f.w;
        }
    } else {
#pragma unroll
        for (int i = 0; i < 32; ++i) {
            const int k = 288 + i;
            v[i] = (k < 300) ? A[(size_t)row * 300 + k] : 0.f;
        }
    }
    const int r128 = row & 127;
    const int xr = (r128 >> 1) & 3;
    const size_t tb = ((size_t)(row >> 7) * 10 + ch) * 4096 + r128 * 32;
#pragma unroll
    for (int sub = 0; sub < 4; ++sub) {
        const int slot = sub ^ xr;
        u16x8 hv, lv;
#pragma unroll
        for (int e = 0; e < 8; ++e) {
            const float f = v[sub * 8 + e];
            const unsigned short h = f2bf(f);
            hv[e] = h; lv[e] = f2bf(f - bf2f(h));
        }
        *(u16x8*)(H + tb + slot * 8) = hv;
        *(u16x8*)(L + tb + slot * 8) = lv;
    }
}

// ---------------------------------------------------------------------------
// Kernel 1b: WQ/WK/WV -> split bf16 transposed tiled B layout (QSCALE folded
// into WQ); WO -> plain bf16 transposed tiled (n padded 300->384).
// ---------------------------------------------------------------------------
__global__ __launch_bounds__(256) void convW_kernel(
    const float* __restrict__ WQ, const float* __restrict__ WK,
    const float* __restrict__ WV, const float* __restrict__ WO,
    unsigned short* __restrict__ CW, unsigned short* __restrict__ WOT)
{
    const int idx = blockIdx.x * 256 + threadIdx.x;
    if (idx < 122880) {                       // QKV: which x k(320) x n4(128)
        const int which = idx / 40960;
        const int rem = idx - which * 40960;
        const int k = rem >> 7;
        const int n0 = (rem & 127) * 4;
        const float* __restrict__ W = which == 0 ? WQ : (which == 1 ? WK : WV);
        unsigned short* __restrict__ H = CW + (size_t)which * 327680;
        unsigned short* __restrict__ L = H + 163840;
        const float sc = (which == 0) ? QSCALE : 1.f;
        float4 w = make_float4(0.f, 0.f, 0.f, 0.f);
        if (k < 300) w = *(const float4*)(W + (size_t)k * 512 + n0);
        const float wv4[4] = {w.x * sc, w.y * sc, w.z * sc, w.w * sc};
        const int ch = k >> 5, kk = k & 31;
#pragma unroll
        for (int j = 0; j < 4; ++j) {
            const int n = n0 + j, ntile = n >> 7, nr = n & 127;
            const size_t o = ((size_t)(ntile * 10 + ch) * 128 + nr) * 32
                           + (((kk >> 3) ^ ((nr >> 1) & 3)) << 3) + (kk & 7);
            const unsigned short h = f2bf(wv4[j]);
            H[o] = h; L[o] = f2bf(wv4[j] - bf2f(h));
        }
    } else {                                   // WO: k(512) x n4(96)
        const int idx2 = idx - 122880;
        const int k = idx2 / 96, n4 = idx2 - k * 96;
        const int n0 = n4 * 4;
        float4 w = make_float4(0.f, 0.f, 0.f, 0.f);
        if (n0 < 300) w = *(const float4*)(WO + (size_t)k * 300 + n0);
        const float wv4[4] = {w.x, w.y, w.z, w.w};
        const int ch = k >> 5, kk = k & 31;
#pragma unroll
        for (int j = 0; j < 4; ++j) {
            const int n = n0 + j, ntile = n >> 7, nr = n & 127;
            const size_t o = ((size_t)(ntile * 16 + ch) * 128 + nr) * 32
                           + (((kk >> 3) ^ ((nr >> 1) & 3)) << 3) + (kk & 7);
            WOT[o] = f2bf(wv4[j]);
        }
    }
}

// ---------------------------------------------------------------------------
// Kernel 2: MFMA QKV projection, 3-term split bf16 (Ah*Wh+Ah*Wl+Al*Wh).
// grid (64 s-tiles, 4 n-tiles, 3 which), block 256 = 4 waves (2x2 of 64x64).
// K=320 in 10 chunks of 32, LDS double-buffered via global_load_lds.
// ---------------------------------------------------------------------------
__global__ __launch_bounds__(256) void proj_mfma_kernel(
    const unsigned short* __restrict__ CA, const unsigned short* __restrict__ CW,
    unsigned short* __restrict__ Qh, unsigned short* __restrict__ Ql,
    unsigned short* __restrict__ KhT, unsigned short* __restrict__ KlT,
    unsigned short* __restrict__ VtT)
{
    const int stile = blockIdx.x, jtile = blockIdx.y, which = blockIdx.z;
    const int tid = threadIdx.x, wv = tid >> 6, lane = tid & 63;
    const int li = lane & 15, g = lane >> 4;
    const int wr = wv >> 1, wc = wv & 1;

    __shared__ __align__(16) char LBp[65536];   // 2 bufs x (Ah|Al|Wh|Wl) x 8KB

    const unsigned short* __restrict__ pAh =
        CA + (size_t)(which ? 1 : 0) * 5242880 + (size_t)stile * 40960 + tid * 8;
    const unsigned short* __restrict__ pAl = pAh + 2621440;
    const unsigned short* __restrict__ pWh =
        CW + (size_t)which * 327680 + (size_t)jtile * 40960 + tid * 8;
    const unsigned short* __restrict__ pWl = pWh + 163840;

#define STAGEP(ch, bofs) {                                                    \
        char* db = LBp + (bofs) + wv * 1024;                                  \
        const size_t co = (size_t)(ch) * 4096;                                \
        gload16(pAh + co,        db);                                         \
        gload16(pAh + co + 2048, db + 4096);                                  \
        gload16(pAl + co,        db + 8192);                                  \
        gload16(pAl + co + 2048, db + 12288);                                 \
        gload16(pWh + co,        db + 16384);                                 \
        gload16(pWh + co + 2048, db + 20480);                                 \
        gload16(pWl + co,        db + 24576);                                 \
        gload16(pWl + co + 2048, db + 28672);                                 \
    }

    int offA[4], offW[4];
#pragma unroll
    for (int ssub = 0; ssub < 4; ++ssub) {
        const int r = wr * 64 + ssub * 16 + li;
        offA[ssub] = r * 64 + ((g ^ ((r >> 1) & 3)) << 4);
    }
#pragma unroll
    for (int jsub = 0; jsub < 4; ++jsub) {
        const int n = wc * 64 + jsub * 16 + li;
        offW[jsub] = n * 64 + ((g ^ ((n >> 1) & 3)) << 4);
    }

    f32x4 acc[4][4];
#pragma unroll
    for (int i = 0; i < 4; ++i)
#pragma unroll
        for (int j = 0; j < 4; ++j) acc[i][j] = (f32x4){0.f, 0.f, 0.f, 0.f};

    STAGEP(0, 0)
    __syncthreads();

#pragma unroll 1
    for (int ch = 0; ch < 10; ++ch) {
        const int bofs = (ch & 1) * 32768;
        if (ch < 9) STAGEP(ch + 1, bofs ^ 32768)
        const char* bp = LBp + bofs;
        s16x8 ah[4], al[4], wh[4], wl[4];
#pragma unroll
        for (int ssub = 0; ssub < 4; ++ssub) {
            ah[ssub] = *(const s16x8*)(bp + offA[ssub]);
            al[ssub] = *(const s16x8*)(bp + 8192 + offA[ssub]);
        }
#pragma unroll
        for (int jsub = 0; jsub < 4; ++jsub) {
            wh[jsub] = *(const s16x8*)(bp + 16384 + offW[jsub]);
            wl[jsub] = *(const s16x8*)(bp + 24576 + offW[jsub]);
        }
#pragma unroll
        for (int ssub = 0; ssub < 4; ++ssub)
#pragma unroll
            for (int jsub = 0; jsub < 4; ++jsub) {
                acc[ssub][jsub] = MFMA16(ah[ssub], wh[jsub], acc[ssub][jsub], 0, 0, 0);
                acc[ssub][jsub] = MFMA16(ah[ssub], wl[jsub], acc[ssub][jsub], 0, 0, 0);
                acc[ssub][jsub] = MFMA16(al[ssub], wh[jsub], acc[ssub][jsub], 0, 0, 0);
            }
        __syncthreads();
    }
#undef STAGEP

    // epilogue: D frag (ssub,jsub): n = jg = jtile*128+wc*64+jsub*16+li (fixed),
    // m = s = stile*128+wr*64+ssub*16+4g+r
    const int jgbase = jtile * 128 + wc * 64 + li;
    const int sbase0 = stile * 128 + wr * 64 + 4 * g;
#pragma unroll
    for (int jsub = 0; jsub < 4; ++jsub) {
        const int jgg = jgbase + jsub * 16;
        const int d = jgg >> 3, hh = jgg & 7;
#pragma unroll
        for (int ssub = 0; ssub < 4; ++ssub) {
            const f32x4 v = acc[ssub][jsub];
            const int sg0 = sbase0 + ssub * 16;
            const int bbv = sg0 >> 11;
            const int bhn = bbv * 8 + hh;
            const int sl0 = sg0 & 2047;
            if (which == 0) {
                const size_t o = ((size_t)bhn * 2048 + sl0) * 64 + d;
#pragma unroll
                for (int r = 0; r < 4; ++r) {
                    const float val = v[r];
                    const unsigned short hi = f2bf(val);
                    Qh[o + r * 64] = hi;
                    Ql[o + r * 64] = f2bf(val - bf2f(hi));
                }
            } else if (which == 1) {
                const int tile = sl0 >> 6, tt0 = sl0 & 63;
                const size_t tb = ((size_t)(bhn * 32 + tile)) << 12;
#pragma unroll
                for (int r = 0; r < 4; ++r) {
                    const int tt = tt0 + r;
                    const size_t o = tb + tt * 64 + (((d >> 3) ^ (tt & 7)) << 3) + (d & 7);
                    const float val = v[r];
                    const unsigned short hi = f2bf(val);
                    KhT[o] = hi;
                    KlT[o] = f2bf(val - bf2f(hi));
                }
            } else {
                const int tile = sl0 >> 6, tin0 = sl0 & 63;
                const size_t tb = ((size_t)(bhn * 32 + tile)) << 12;
                const int blk = tin0 >> 5, gg2 = (tin0 >> 2) & 3, half = (tin0 >> 4) & 1;
                const size_t o = tb + (size_t)d * 64
                               + ((((blk << 2) | gg2) ^ (d & 7)) << 3) + half * 4;
                u16x4 pk;
#pragma unroll
                for (int r = 0; r < 4; ++r) pk[r] = f2bf(v[r]);
                *(u16x4*)(VtT + o) = pk;
            }
        }
    }
}

// ---------------------------------------------------------------------------
// Kernel 3: MFMA flash attention (unchanged core), epilogue stores AO as bf16
// in the epi-GEMM tiled A layout.
// ---------------------------------------------------------------------------
__global__ __launch_bounds__(512, 4) void attn_mfma_kernel(
    const unsigned short* __restrict__ Qh, const unsigned short* __restrict__ Ql,
    const unsigned short* __restrict__ KhT, const unsigned short* __restrict__ KlT,
    const unsigned short* __restrict__ VtT, const unsigned short* __restrict__ BiasP,
    unsigned short* __restrict__ AOb)
{
    const int qt = blockIdx.x, bh = blockIdx.y;
    const int bb = bh >> 3, hh = bh & 7;
    const int tid = threadIdx.x;
    const int wv = tid >> 6, lane = tid & 63;
    const int g = lane >> 4, li = lane & 15;
    const int q = qt * 128 + wv * 16 + li;

    __shared__ __align__(16) char LB[2 * BUFB];

    const size_t qoff = ((size_t)bh * SD_ + q) * DH + 8 * g;
    const s16x8 qh0 = *(const s16x8*)(Qh + qoff);
    const s16x8 qh1 = *(const s16x8*)(Qh + qoff + 32);
    const s16x8 ql0 = *(const s16x8*)(Ql + qoff);
    const s16x8 ql1 = *(const s16x8*)(Ql + qoff + 32);

    const unsigned short* __restrict__ sKh = KhT + ((size_t)bh << 17) + tid * 8;
    const unsigned short* __restrict__ sKl = KlT + ((size_t)bh << 17) + tid * 8;
    const unsigned short* __restrict__ sVt = VtT + ((size_t)bh << 17) + tid * 8;

    const int base0 = li * 128 + ((g ^ (li & 7)) << 4);
    const int base1 = li * 128 + (((4 + g) ^ (li & 7)) << 4);

#define STAGE(tile, boff)                                                     \
    {                                                                         \
        char* db = LB + (boff) + wv * 1024;                                   \
        const size_t toff = (size_t)(tile) << 12;                             \
        gload16(sKh + toff, db);                                              \
        gload16(sKl + toff, db + 8192);                                       \
        gload16(sVt + toff, db + 16384);                                      \
    }

    float m = -INFINITY, l = 0.f;
    f32x4 O[4];
#pragma unroll
    for (int i = 0; i < 4; ++i) O[i] = (f32x4){0.f, 0.f, 0.f, 0.f};

    STAGE(0, 0)
    unsigned short bw = BiasP[(size_t)q * 128 + g];
    __syncthreads();

    int bufoff = 0;
#pragma unroll 1
    for (int it = 0; it < 32; ++it) {
        const int nxt = (it + 1) & 31;
        STAGE(nxt, bufoff ^ BUFB)
        const unsigned short bwN = BiasP[(size_t)q * 128 + nxt * 4 + g];

        f32x4 s[4];
#pragma unroll
        for (int sub = 0; sub < 4; ++sub)
#pragma unroll
            for (int c = 0; c < 4; ++c)
                s[sub][c] = ((bw >> (sub * 4 + c)) & 1) ? NEGL : 0.f;

#pragma unroll
        for (int sub = 0; sub < 4; ++sub) {
            const s16x8 kh0 = *(const s16x8*)(LB + bufoff + base0 + sub * 2048);
            const s16x8 kh1 = *(const s16x8*)(LB + bufoff + base1 + sub * 2048);
            const s16x8 kl0 = *(const s16x8*)(LB + bufoff + base0 + 8192 + sub * 2048);
            const s16x8 kl1 = *(const s16x8*)(LB + bufoff + base1 + 8192 + sub * 2048);
            s[sub] = MFMA16(kh0, qh0, s[sub], 0, 0, 0);
            s[sub] = MFMA16(kh0, ql0, s[sub], 0, 0, 0);
            s[sub] = MFMA16(kl0, qh0, s[sub], 0, 0, 0);
            s[sub] = MFMA16(kh1, qh1, s[sub], 0, 0, 0);
            s[sub] = MFMA16(kh1, ql1, s[sub], 0, 0, 0);
            s[sub] = MFMA16(kl1, qh1, s[sub], 0, 0, 0);
        }

        float tmax = fmaxf(fmaxf(s[0][0], s[0][1]), fmaxf(s[0][2], s[0][3]));
        tmax = fmaxf(tmax, fmaxf(fmaxf(s[1][0], s[1][1]), fmaxf(s[1][2], s[1][3])));
        tmax = fmaxf(tmax, fmaxf(fmaxf(s[2][0], s[2][1]), fmaxf(s[2][2], s[2][3])));
        tmax = fmaxf(tmax, fmaxf(fmaxf(s[3][0], s[3][1]), fmaxf(s[3][2], s[3][3])));
        tmax = fmaxf(tmax, __shfl_xor(tmax, 16));
        tmax = fmaxf(tmax, __shfl_xor(tmax, 32));
        const float mn  = fmaxf(m, tmax);
        const float scl = exp2f(m - mn);
        float ps = 0.f;
#pragma unroll
        for (int sub = 0; sub < 4; ++sub)
#pragma unroll
            for (int c = 0; c < 4; ++c) {
                float p = exp2f(s[sub][c] - mn);
                s[sub][c] = p;
                ps += p;
            }
        ps += __shfl_xor(ps, 16);
        ps += __shfl_xor(ps, 32);
        l = l * scl + ps;
        m = mn;
#pragma unroll
        for (int i = 0; i < 4; ++i) O[i] *= scl;

        union { s16x8 v; unsigned int w[4]; } P0, P1;
        asm("v_cvt_pk_bf16_f32 %0, %1, %2" : "=v"(P0.w[0]) : "v"(s[0][0]), "v"(s[0][1]));
        asm("v_cvt_pk_bf16_f32 %0, %1, %2" : "=v"(P0.w[1]) : "v"(s[0][2]), "v"(s[0][3]));
        asm("v_cvt_pk_bf16_f32 %0, %1, %2" : "=v"(P0.w[2]) : "v"(s[1][0]), "v"(s[1][1]));
        asm("v_cvt_pk_bf16_f32 %0, %1, %2" : "=v"(P0.w[3]) : "v"(s[1][2]), "v"(s[1][3]));
        asm("v_cvt_pk_bf16_f32 %0, %1, %2" : "=v"(P1.w[0]) : "v"(s[2][0]), "v"(s[2][1]));
        asm("v_cvt_pk_bf16_f32 %0, %1, %2" : "=v"(P1.w[1]) : "v"(s[2][2]), "v"(s[2][3]));
        asm("v_cvt_pk_bf16_f32 %0, %1, %2" : "=v"(P1.w[2]) : "v"(s[3][0]), "v"(s[3][1]));
        asm("v_cvt_pk_bf16_f32 %0, %1, %2" : "=v"(P1.w[3]) : "v"(s[3][2]), "v"(s[3][3]));

#pragma unroll
        for (int dsub = 0; dsub < 4; ++dsub) {
            const s16x8 vf0 = *(const s16x8*)(LB + bufoff + base0 + 16384 + dsub * 2048);
            const s16x8 vf1 = *(const s16x8*)(LB + bufoff + base1 + 16384 + dsub * 2048);
            O[dsub] = MFMA16(vf0, P0.v, O[dsub], 0, 0, 0);
            O[dsub] = MFMA16(vf1, P1.v, O[dsub], 0, 0, 0);
        }

        bw = bwN;
        __syncthreads();
        bufoff ^= BUFB;
    }

    // epilogue: AO row = bb*2048+q, col = hh*64 + dsub*16 + 4g + c -> bf16
    // tiled layout for the epi GEMM
    const float rl = 1.f / l;
    const int row = bb * 2048 + q;
    const int r128 = row & 127;
    const int xr = (r128 >> 1) & 3;
    unsigned short* __restrict__ ab = AOb + ((size_t)(row >> 7)) * 65536
                                    + r128 * 32 + (g & 1) * 4;
#pragma unroll
    for (int dsub = 0; dsub < 4; ++dsub) {
        const f32x4 o = O[dsub] * rl;
        const int ch = hh * 2 + (dsub >> 1);
        const int slot = ((dsub & 1) * 2 + (g >> 1)) ^ xr;
        u16x4 pk;
#pragma unroll
        for (int c = 0; c < 4; ++c) pk[c] = f2bf(o[c]);
        *(u16x4*)(ab + (size_t)ch * 4096 + slot * 8) = pk;
    }
#undef STAGE
}

// ---------------------------------------------------------------------------
// Kernel 4: MFMA epilogue GEMM AObf[8192,512] @ WO[512,300] -> out fp32.
// grid (64 s-tiles, 3 n-tiles), block 256 = 4 waves (2x2 of 64x64), 16 chunks.
// ---------------------------------------------------------------------------
__global__ __launch_bounds__(256) void epi_mfma_kernel(
    const unsigned short* __restrict__ AOb, const unsigned short* __restrict__ WOT,
    float* __restrict__ out)
{
    const int stile = blockIdx.x, jtile = blockIdx.y;
    const int tid = threadIdx.x, wv = tid >> 6, lane = tid & 63;
    const int li = lane & 15, g = lane >> 4;
    const int wr = wv >> 1, wc = wv & 1;

    __shared__ __align__(16) char LBe[32768];   // 2 bufs x (A|W) x 8KB

    const unsigned short* __restrict__ pA = AOb + (size_t)stile * 65536 + tid * 8;
    const unsigned short* __restrict__ pW = WOT + (size_t)jtile * 65536 + tid * 8;

#define STAGEE(ch, bofs) {                                                    \
        char* db = LBe + (bofs) + wv * 1024;                                  \
        const size_t co = (size_t)(ch) * 4096;                                \
        gload16(pA + co,        db);                                          \
        gload16(pA + co + 2048, db + 4096);                                   \
        gload16(pW + co,        db + 8192);                                   \
        gload16(pW + co + 2048, db + 12288);                                  \
    }

    int offA[4], offW[4];
#pragma unroll
    for (int ssub = 0; ssub < 4; ++ssub) {
        const int r = wr * 64 + ssub * 16 + li;
        offA[ssub] = r * 64 + ((g ^ ((r >> 1) & 3)) << 4);
    }
#pragma unroll
    for (int jsub = 0; jsub < 4; ++jsub) {
        const int n = wc * 64 + jsub * 16 + li;
        offW[jsub] = n * 64 + ((g ^ ((n >> 1) & 3)) << 4);
    }

    f32x4 acc[4][4];
#pragma unroll
    for (int i = 0; i < 4; ++i)
#pragma unroll
        for (int j = 0; j < 4; ++j) acc[i][j] = (f32x4){0.f, 0.f, 0.f, 0.f};

    STAGEE(0, 0)
    __syncthreads();

#pragma unroll 1
    for (int ch = 0; ch < 16; ++ch) {
        const int bofs = (ch & 1) * 16384;
        if (ch < 15) STAGEE(ch + 1, bofs ^ 16384)
        const char* bp = LBe + bofs;
        s16x8 ah[4], wh[4];
#pragma unroll
        for (int ssub = 0; ssub < 4; ++ssub)
            ah[ssub] = *(const s16x8*)(bp + offA[ssub]);
#pragma unroll
        for (int jsub = 0; jsub < 4; ++jsub)
            wh[jsub] = *(const s16x8*)(bp + 8192 + offW[jsub]);
#pragma unroll
        for (int ssub = 0; ssub < 4; ++ssub)
#pragma unroll
            for (int jsub = 0; jsub < 4; ++jsub)
                acc[ssub][jsub] = MFMA16(ah[ssub], wh[jsub], acc[ssub][jsub], 0, 0, 0);
        __syncthreads();
    }
#undef STAGEE

    const int jgbase = jtile * 128 + wc * 64 + li;
    const int sbase0 = stile * 128 + wr * 64 + 4 * g;
#pragma unroll
    for (int jsub = 0; jsub < 4; ++jsub) {
        const int o = jgbase + jsub * 16;
        if (o < HIDIN) {
#pragma unroll
            for (int ssub = 0; ssub < 4; ++ssub) {
                const f32x4 v = acc[ssub][jsub];
                const int sg0 = sbase0 + ssub * 16;
#pragma unroll
                for (int r = 0; r < 4; ++r)
                    out[(size_t)(sg0 + r) * HIDIN + o] = v[r];
            }
        }
    }
}

// ---------------------------------------------------------------------------
extern "C" void kernel_launch(void* const* d_in, const int* in_sizes, int n_in,
                              void* d_out, int out_size, void* d_ws, size_t ws_size,
                              hipStream_t stream)
{
    const float* en  = (const float*)d_in[0];
    const float* de  = (const float*)d_in[1];
    const int*   mask = (const int*)d_in[2];
    const float* WQ  = (const float*)d_in[3];
    const float* WK  = (const float*)d_in[4];
    const float* WV  = (const float*)d_in[5];
    const float* WO  = (const float*)d_in[6];
    float* out = (float*)d_out;

    unsigned short* ws2 = (unsigned short*)d_ws;
    unsigned short* Qh  = ws2 + OF_QH;
    unsigned short* Ql  = ws2 + OF_QL;
    unsigned short* KhT = ws2 + OF_KH;
    unsigned short* KlT = ws2 + OF_KL;
    unsigned short* VtT = ws2 + OF_VT;
    unsigned long long* BiasB = (unsigned long long*)(ws2 + OF_BB);
    unsigned short* CA  = ws2 + OF_CA;
    unsigned short* CW  = ws2 + OF_CW;
    unsigned short* WOT = ws2 + OF_WOT;
    unsigned short* AOb = CA;    // aliases conv-A area (dead after proj)

    bias_kernel<<<dim3(256), 256, 0, stream>>>(mask, BiasB);
    convA_kernel<<<dim3(320, 2), 256, 0, stream>>>(de, en, CA);
    convW_kernel<<<dim3(672), 256, 0, stream>>>(WQ, WK, WV, WO, CW, WOT);
    proj_mfma_kernel<<<dim3(64, 4, 3), 256, 0, stream>>>(CA, CW, Qh, Ql, KhT, KlT, VtT);
    attn_mfma_kernel<<<dim3(16, 32), 512, 0, stream>>>(Qh, Ql, KhT, KlT, VtT,
                                                       (const unsigned short*)BiasB, AOb);
    epi_mfma_kernel<<<dim3(64, 3), 256, 0, stream>>>(AOb, WOT, out);
}

// Round 7
// 191.113 us; speedup vs baseline: 4.9886x; 1.0052x over previous
//
#include <hip/hip_runtime.h>
#include <hip/hip_bf16.h>
#include <math.h>

#define B_      4
#define SD_     2048
#define SE_     2048
#define HIDIN   300
#define HIDMID  512
#define NH      8
#define DH      64
#define ESZ     ((size_t)4194304)          // elems per [32][2048][64] tensor
#define BUFB    24576                       // bytes per attn LDS buffer (Kh+Kl+V)

typedef __attribute__((ext_vector_type(8))) short          s16x8;
typedef __attribute__((ext_vector_type(8))) unsigned short u16x8;
typedef __attribute__((ext_vector_type(4))) unsigned short u16x4;
typedef __attribute__((ext_vector_type(4))) float          f32x4;

#define MFMA16 __builtin_amdgcn_mfma_f32_16x16x32_bf16

// logit scale: (1/sqrt(300)) * log2(e)  -> softmax done in base-2
#define QSCALE  0.0832940411f
#define NEGL   -1.4426950e9f               // -1e9 * log2e
#define DEFER_THR 24.0f                    // defer-max threshold (base-2 units)

__device__ __forceinline__ unsigned short f2bf(float f) {
    unsigned int u = __float_as_uint(f);
    u += 0x7fffu + ((u >> 16) & 1u);          // RNE
    return (unsigned short)(u >> 16);
}
__device__ __forceinline__ float bf2f(unsigned short s) {
    return __uint_as_float((unsigned int)s << 16);
}
__device__ __forceinline__ void gload16(const void* g, void* l) {
    __builtin_amdgcn_global_load_lds(
        (const __attribute__((address_space(1))) void*)g,
        (__attribute__((address_space(3))) void*)l, 16, 0, 0);
}

// ws ushort offsets
#define OF_QH   ((size_t)0)
#define OF_QL   (ESZ)
#define OF_KH   (2*ESZ)
#define OF_KL   (3*ESZ)
#define OF_VT   (4*ESZ)
#define OF_BB   (5*ESZ)                    // 262144 ushorts of bias bits
#define OF_CA   (5*ESZ + 262144)           // deH,deL,enH,enL (4 x 2621440)
#define OF_CW   (OF_CA + 10485760)         // WQh,WQl,WKh,WKl,WVh,WVl (6 x 163840)
#define OF_WOT  (OF_CW + 983040)           // 196608

// ---------------------------------------------------------------------------
// Kernel 0: mask (int32) -> packed bits. One u64 per (q, 64-t tile).
// ---------------------------------------------------------------------------
__global__ __launch_bounds__(256) void bias_kernel(const int* __restrict__ mask,
                                                   unsigned long long* __restrict__ BiasB)
{
    const int idx = blockIdx.x * 256 + threadIdx.x;    // 65536 threads
    const int q = idx >> 5, tile = idx & 31;
    const int* __restrict__ mrow = mask + (size_t)q * SE_ + tile * 64;
    unsigned long long w = 0;
#pragma unroll
    for (int sub = 0; sub < 4; ++sub)
#pragma unroll
        for (int gv = 0; gv < 4; ++gv) {
            const int4 mm = *(const int4*)(mrow + sub * 16 + gv * 4);
            const int bp = gv * 16 + sub * 4;
            if (mm.x) w |= 1ull << bp;
            if (mm.y) w |= 1ull << (bp + 1);
            if (mm.z) w |= 1ull << (bp + 2);
            if (mm.w) w |= 1ull << (bp + 3);
        }
    BiasB[idx] = w;
}

// ---------------------------------------------------------------------------
// Kernel 1a: de/en fp32 -> split bf16 hi/lo, tiled GEMM-A layout.
// ---------------------------------------------------------------------------
__global__ __launch_bounds__(256) void convA_kernel(
    const float* __restrict__ de, const float* __restrict__ en,
    unsigned short* __restrict__ CA)
{
    const int idx = blockIdx.x * 256 + threadIdx.x;    // 81920 per matrix
    const int mat = blockIdx.y;
    const float* __restrict__ A = mat ? en : de;
    unsigned short* __restrict__ H = CA + (size_t)mat * 5242880;
    unsigned short* __restrict__ L = H + 2621440;
    const int row = idx / 10, ch = idx - row * 10;
    float v[32];
    if (ch < 9) {
#pragma unroll
        for (int i = 0; i < 8; ++i) {
            const float4 f = *(const float4*)(A + (size_t)row * 300 + ch * 32 + i * 4);
            v[i*4+0] = f.x; v[i*4+1] = f.y; v[i*4+2] = f.z; v[i*4+3] = f.w;
        }
    } else {
#pragma unroll
        for (int i = 0; i < 32; ++i) {
            const int k = 288 + i;
            v[i] = (k < 300) ? A[(size_t)row * 300 + k] : 0.f;
        }
    }
    const int r128 = row & 127;
    const int xr = (r128 >> 1) & 3;
    const size_t tb = ((size_t)(row >> 7) * 10 + ch) * 4096 + r128 * 32;
#pragma unroll
    for (int sub = 0; sub < 4; ++sub) {
        const int slot = sub ^ xr;
        u16x8 hv, lv;
#pragma unroll
        for (int e = 0; e < 8; ++e) {
            const float f = v[sub * 8 + e];
            const unsigned short h = f2bf(f);
            hv[e] = h; lv[e] = f2bf(f - bf2f(h));
        }
        *(u16x8*)(H + tb + slot * 8) = hv;
        *(u16x8*)(L + tb + slot * 8) = lv;
    }
}

// ---------------------------------------------------------------------------
// Kernel 1b: WQ/WK/WV -> split bf16 transposed tiled B layout (QSCALE folded
// into WQ); WO -> plain bf16 transposed tiled (n padded 300->384).
// ---------------------------------------------------------------------------
__global__ __launch_bounds__(256) void convW_kernel(
    const float* __restrict__ WQ, const float* __restrict__ WK,
    const float* __restrict__ WV, const float* __restrict__ WO,
    unsigned short* __restrict__ CW, unsigned short* __restrict__ WOT)
{
    const int idx = blockIdx.x * 256 + threadIdx.x;
    if (idx < 122880) {                       // QKV: which x k(320) x n4(128)
        const int which = idx / 40960;
        const int rem = idx - which * 40960;
        const int k = rem >> 7;
        const int n0 = (rem & 127) * 4;
        const float* __restrict__ W = which == 0 ? WQ : (which == 1 ? WK : WV);
        unsigned short* __restrict__ H = CW + (size_t)which * 327680;
        unsigned short* __restrict__ L = H + 163840;
        const float sc = (which == 0) ? QSCALE : 1.f;
        float4 w = make_float4(0.f, 0.f, 0.f, 0.f);
        if (k < 300) w = *(const float4*)(W + (size_t)k * 512 + n0);
        const float wv4[4] = {w.x * sc, w.y * sc, w.z * sc, w.w * sc};
        const int ch = k >> 5, kk = k & 31;
#pragma unroll
        for (int j = 0; j < 4; ++j) {
            const int n = n0 + j, ntile = n >> 7, nr = n & 127;
            const size_t o = ((size_t)(ntile * 10 + ch) * 128 + nr) * 32
                           + (((kk >> 3) ^ ((nr >> 1) & 3)) << 3) + (kk & 7);
            const unsigned short h = f2bf(wv4[j]);
            H[o] = h; L[o] = f2bf(wv4[j] - bf2f(h));
        }
    } else {                                   // WO: k(512) x n4(96)
        const int idx2 = idx - 122880;
        const int k = idx2 / 96, n4 = idx2 - k * 96;
        const int n0 = n4 * 4;
        float4 w = make_float4(0.f, 0.f, 0.f, 0.f);
        if (n0 < 300) w = *(const float4*)(WO + (size_t)k * 300 + n0);
        const float wv4[4] = {w.x, w.y, w.z, w.w};
        const int ch = k >> 5, kk = k & 31;
#pragma unroll
        for (int j = 0; j < 4; ++j) {
            const int n = n0 + j, ntile = n >> 7, nr = n & 127;
            const size_t o = ((size_t)(ntile * 16 + ch) * 128 + nr) * 32
                           + (((kk >> 3) ^ ((nr >> 1) & 3)) << 3) + (kk & 7);
            WOT[o] = f2bf(wv4[j]);
        }
    }
}

// ---------------------------------------------------------------------------
// Kernel 2: MFMA QKV projection, 3-term split bf16.
// ---------------------------------------------------------------------------
__global__ __launch_bounds__(256) void proj_mfma_kernel(
    const unsigned short* __restrict__ CA, const unsigned short* __restrict__ CW,
    unsigned short* __restrict__ Qh, unsigned short* __restrict__ Ql,
    unsigned short* __restrict__ KhT, unsigned short* __restrict__ KlT,
    unsigned short* __restrict__ VtT)
{
    const int stile = blockIdx.x, jtile = blockIdx.y, which = blockIdx.z;
    const int tid = threadIdx.x, wv = tid >> 6, lane = tid & 63;
    const int li = lane & 15, g = lane >> 4;
    const int wr = wv >> 1, wc = wv & 1;

    __shared__ __align__(16) char LBp[65536];   // 2 bufs x (Ah|Al|Wh|Wl) x 8KB

    const unsigned short* __restrict__ pAh =
        CA + (size_t)(which ? 1 : 0) * 5242880 + (size_t)stile * 40960 + tid * 8;
    const unsigned short* __restrict__ pAl = pAh + 2621440;
    const unsigned short* __restrict__ pWh =
        CW + (size_t)which * 327680 + (size_t)jtile * 40960 + tid * 8;
    const unsigned short* __restrict__ pWl = pWh + 163840;

#define STAGEP(ch, bofs) {                                                    \
        char* db = LBp + (bofs) + wv * 1024;                                  \
        const size_t co = (size_t)(ch) * 4096;                                \
        gload16(pAh + co,        db);                                         \
        gload16(pAh + co + 2048, db + 4096);                                  \
        gload16(pAl + co,        db + 8192);                                  \
        gload16(pAl + co + 2048, db + 12288);                                 \
        gload16(pWh + co,        db + 16384);                                 \
        gload16(pWh + co + 2048, db + 20480);                                 \
        gload16(pWl + co,        db + 24576);                                 \
        gload16(pWl + co + 2048, db + 28672);                                 \
    }

    int offA[4], offW[4];
#pragma unroll
    for (int ssub = 0; ssub < 4; ++ssub) {
        const int r = wr * 64 + ssub * 16 + li;
        offA[ssub] = r * 64 + ((g ^ ((r >> 1) & 3)) << 4);
    }
#pragma unroll
    for (int jsub = 0; jsub < 4; ++jsub) {
        const int n = wc * 64 + jsub * 16 + li;
        offW[jsub] = n * 64 + ((g ^ ((n >> 1) & 3)) << 4);
    }

    f32x4 acc[4][4];
#pragma unroll
    for (int i = 0; i < 4; ++i)
#pragma unroll
        for (int j = 0; j < 4; ++j) acc[i][j] = (f32x4){0.f, 0.f, 0.f, 0.f};

    STAGEP(0, 0)
    __syncthreads();

#pragma unroll 1
    for (int ch = 0; ch < 10; ++ch) {
        const int bofs = (ch & 1) * 32768;
        if (ch < 9) STAGEP(ch + 1, bofs ^ 32768)
        const char* bp = LBp + bofs;
        s16x8 ah[4], al[4], wh[4], wl[4];
#pragma unroll
        for (int ssub = 0; ssub < 4; ++ssub) {
            ah[ssub] = *(const s16x8*)(bp + offA[ssub]);
            al[ssub] = *(const s16x8*)(bp + 8192 + offA[ssub]);
        }
#pragma unroll
        for (int jsub = 0; jsub < 4; ++jsub) {
            wh[jsub] = *(const s16x8*)(bp + 16384 + offW[jsub]);
            wl[jsub] = *(const s16x8*)(bp + 24576 + offW[jsub]);
        }
        __builtin_amdgcn_s_setprio(1);
#pragma unroll
        for (int ssub = 0; ssub < 4; ++ssub)
#pragma unroll
            for (int jsub = 0; jsub < 4; ++jsub) {
                acc[ssub][jsub] = MFMA16(ah[ssub], wh[jsub], acc[ssub][jsub], 0, 0, 0);
                acc[ssub][jsub] = MFMA16(ah[ssub], wl[jsub], acc[ssub][jsub], 0, 0, 0);
                acc[ssub][jsub] = MFMA16(al[ssub], wh[jsub], acc[ssub][jsub], 0, 0, 0);
            }
        __builtin_amdgcn_s_setprio(0);
        __syncthreads();
    }
#undef STAGEP

    const int jgbase = jtile * 128 + wc * 64 + li;
    const int sbase0 = stile * 128 + wr * 64 + 4 * g;
#pragma unroll
    for (int jsub = 0; jsub < 4; ++jsub) {
        const int jgg = jgbase + jsub * 16;
        const int d = jgg >> 3, hh = jgg & 7;
#pragma unroll
        for (int ssub = 0; ssub < 4; ++ssub) {
            const f32x4 v = acc[ssub][jsub];
            const int sg0 = sbase0 + ssub * 16;
            const int bbv = sg0 >> 11;
            const int bhn = bbv * 8 + hh;
            const int sl0 = sg0 & 2047;
            if (which == 0) {
                const size_t o = ((size_t)bhn * 2048 + sl0) * 64 + d;
#pragma unroll
                for (int r = 0; r < 4; ++r) {
                    const float val = v[r];
                    const unsigned short hi = f2bf(val);
                    Qh[o + r * 64] = hi;
                    Ql[o + r * 64] = f2bf(val - bf2f(hi));
                }
            } else if (which == 1) {
                const int tile = sl0 >> 6, tt0 = sl0 & 63;
                const size_t tb = ((size_t)(bhn * 32 + tile)) << 12;
#pragma unroll
                for (int r = 0; r < 4; ++r) {
                    const int tt = tt0 + r;
                    const size_t o = tb + tt * 64 + (((d >> 3) ^ (tt & 7)) << 3) + (d & 7);
                    const float val = v[r];
                    const unsigned short hi = f2bf(val);
                    KhT[o] = hi;
                    KlT[o] = f2bf(val - bf2f(hi));
                }
            } else {
                const int tile = sl0 >> 6, tin0 = sl0 & 63;
                const size_t tb = ((size_t)(bhn * 32 + tile)) << 12;
                const int blk = tin0 >> 5, gg2 = (tin0 >> 2) & 3, half = (tin0 >> 4) & 1;
                const size_t o = tb + (size_t)d * 64
                               + ((((blk << 2) | gg2) ^ (d & 7)) << 3) + half * 4;
                u16x4 pk;
#pragma unroll
                for (int r = 0; r < 4; ++r) pk[r] = f2bf(v[r]);
                *(u16x4*)(VtT + o) = pk;
            }
        }
    }
}

// ---------------------------------------------------------------------------
// Kernel 3: MFMA flash attention. 3-buffer ring + counted vmcnt (T3/T4),
// setprio (T5), XCD-aware block swizzle (T1), defer-max (T13).
// ---------------------------------------------------------------------------
__global__ __launch_bounds__(512, 4) void attn_mfma_kernel(
    const unsigned short* __restrict__ Qh, const unsigned short* __restrict__ Ql,
    const unsigned short* __restrict__ KhT, const unsigned short* __restrict__ KlT,
    const unsigned short* __restrict__ VtT, const unsigned short* __restrict__ BiasP,
    unsigned short* __restrict__ AOb)
{
    // XCD swizzle: lin%8 = XCD; give each XCD 4 heads x all 16 q-tiles.
    const int lin = blockIdx.x + 16 * blockIdx.y;
    const int qt = (lin >> 3) & 15;
    const int bh = (lin & 7) + ((lin >> 7) << 3);
    const int bb = bh >> 3, hh = bh & 7;
    const int tid = threadIdx.x;
    const int wv = tid >> 6, lane = tid & 63;
    const int g = lane >> 4, li = lane & 15;
    const int q = qt * 128 + wv * 16 + li;

    __shared__ __align__(16) char LB[3 * BUFB];

    const size_t qoff = ((size_t)bh * SD_ + q) * DH + 8 * g;
    const s16x8 qh0 = *(const s16x8*)(Qh + qoff);
    const s16x8 qh1 = *(const s16x8*)(Qh + qoff + 32);
    const s16x8 ql0 = *(const s16x8*)(Ql + qoff);
    const s16x8 ql1 = *(const s16x8*)(Ql + qoff + 32);

    const unsigned short* __restrict__ sKh = KhT + ((size_t)bh << 17) + tid * 8;
    const unsigned short* __restrict__ sKl = KlT + ((size_t)bh << 17) + tid * 8;
    const unsigned short* __restrict__ sVt = VtT + ((size_t)bh << 17) + tid * 8;

    const int base0 = li * 128 + ((g ^ (li & 7)) << 4);
    const int base1 = li * 128 + (((4 + g) ^ (li & 7)) << 4);

#define STAGE(tile, boff)                                                     \
    {                                                                         \
        char* db = LB + (boff) + wv * 1024;                                   \
        const size_t toff = (size_t)(tile) << 12;                             \
        gload16(sKh + toff, db);                                              \
        gload16(sKl + toff, db + 8192);                                       \
        gload16(sVt + toff, db + 16384);                                      \
    }

    float m = -INFINITY, l = 0.f;
    f32x4 O[4];
#pragma unroll
    for (int i = 0; i < 4; ++i) O[i] = (f32x4){0.f, 0.f, 0.f, 0.f};

    // prologue: tiles 0,1 -> slots 0,1
    STAGE(0, 0)
    STAGE(1, BUFB)
    unsigned short bw = BiasP[(size_t)q * 128 + g];
    asm volatile("s_waitcnt vmcnt(3)" ::: "memory");   // tile 0 landed
    __builtin_amdgcn_s_barrier();
    __builtin_amdgcn_sched_barrier(0);

    int cc = 0, cs = 2 * BUFB;     // compute slot, stage slot
#pragma unroll 1
    for (int it = 0; it < 32; ++it) {
        STAGE((it + 2) & 31, cs)   // tile it+2 in flight across barriers
        const unsigned short bwN = BiasP[(size_t)q * 128 + (((it + 1) & 31) << 2) + g];

        // ---- acc init from mask bits ----
        f32x4 s[4];
#pragma unroll
        for (int sub = 0; sub < 4; ++sub)
#pragma unroll
            for (int c = 0; c < 4; ++c)
                s[sub][c] = ((bw >> (sub * 4 + c)) & 1) ? NEGL : 0.f;

        // ---- S^T += K Q^T (split bf16) ----
        __builtin_amdgcn_s_setprio(1);
#pragma unroll
        for (int sub = 0; sub < 4; ++sub) {
            const s16x8 kh0 = *(const s16x8*)(LB + cc + base0 + sub * 2048);
            const s16x8 kh1 = *(const s16x8*)(LB + cc + base1 + sub * 2048);
            const s16x8 kl0 = *(const s16x8*)(LB + cc + base0 + 8192 + sub * 2048);
            const s16x8 kl1 = *(const s16x8*)(LB + cc + base1 + 8192 + sub * 2048);
            s[sub] = MFMA16(kh0, qh0, s[sub], 0, 0, 0);
            s[sub] = MFMA16(kh0, ql0, s[sub], 0, 0, 0);
            s[sub] = MFMA16(kl0, qh0, s[sub], 0, 0, 0);
            s[sub] = MFMA16(kh1, qh1, s[sub], 0, 0, 0);
            s[sub] = MFMA16(kh1, ql1, s[sub], 0, 0, 0);
            s[sub] = MFMA16(kl1, qh1, s[sub], 0, 0, 0);
        }
        __builtin_amdgcn_s_setprio(0);

        // ---- online softmax, defer-max (T13). l kept as per-lane partial. ----
        float tmax = fmaxf(fmaxf(s[0][0], s[0][1]), fmaxf(s[0][2], s[0][3]));
        tmax = fmaxf(tmax, fmaxf(fmaxf(s[1][0], s[1][1]), fmaxf(s[1][2], s[1][3])));
        tmax = fmaxf(tmax, fmaxf(fmaxf(s[2][0], s[2][1]), fmaxf(s[2][2], s[2][3])));
        tmax = fmaxf(tmax, fmaxf(fmaxf(s[3][0], s[3][1]), fmaxf(s[3][2], s[3][3])));
        if (__all(tmax <= m + DEFER_THR)) {
            // no rescale: P bounded by 2^24, f32-safe
            float ps = 0.f;
#pragma unroll
            for (int sub = 0; sub < 4; ++sub)
#pragma unroll
                for (int c = 0; c < 4; ++c) {
                    float p = exp2f(s[sub][c] - m);
                    s[sub][c] = p;
                    ps += p;
                }
            l += ps;
        } else {
            tmax = fmaxf(tmax, __shfl_xor(tmax, 16));
            tmax = fmaxf(tmax, __shfl_xor(tmax, 32));
            const float mn  = fmaxf(m, tmax);
            const float scl = exp2f(m - mn);       // exp2(-inf)=0 on first tile
            float ps = 0.f;
#pragma unroll
            for (int sub = 0; sub < 4; ++sub)
#pragma unroll
                for (int c = 0; c < 4; ++c) {
                    float p = exp2f(s[sub][c] - mn);
                    s[sub][c] = p;
                    ps += p;
                }
            l = l * scl + ps;
            m = mn;
#pragma unroll
            for (int i = 0; i < 4; ++i) O[i] *= scl;
        }

        // ---- pack P -> bf16 ----
        union { s16x8 v; unsigned int w[4]; } P0, P1;
        asm("v_cvt_pk_bf16_f32 %0, %1, %2" : "=v"(P0.w[0]) : "v"(s[0][0]), "v"(s[0][1]));
        asm("v_cvt_pk_bf16_f32 %0, %1, %2" : "=v"(P0.w[1]) : "v"(s[0][2]), "v"(s[0][3]));
        asm("v_cvt_pk_bf16_f32 %0, %1, %2" : "=v"(P0.w[2]) : "v"(s[1][0]), "v"(s[1][1]));
        asm("v_cvt_pk_bf16_f32 %0, %1, %2" : "=v"(P0.w[3]) : "v"(s[1][2]), "v"(s[1][3]));
        asm("v_cvt_pk_bf16_f32 %0, %1, %2" : "=v"(P1.w[0]) : "v"(s[2][0]), "v"(s[2][1]));
        asm("v_cvt_pk_bf16_f32 %0, %1, %2" : "=v"(P1.w[1]) : "v"(s[2][2]), "v"(s[2][3]));
        asm("v_cvt_pk_bf16_f32 %0, %1, %2" : "=v"(P1.w[2]) : "v"(s[3][0]), "v"(s[3][1]));
        asm("v_cvt_pk_bf16_f32 %0, %1, %2" : "=v"(P1.w[3]) : "v"(s[3][2]), "v"(s[3][3]));

        // ---- O^T += V^T P^T ----
        __builtin_amdgcn_s_setprio(1);
#pragma unroll
        for (int dsub = 0; dsub < 4; ++dsub) {
            const s16x8 vf0 = *(const s16x8*)(LB + cc + base0 + 16384 + dsub * 2048);
            const s16x8 vf1 = *(const s16x8*)(LB + cc + base1 + 16384 + dsub * 2048);
            O[dsub] = MFMA16(vf0, P0.v, O[dsub], 0, 0, 0);
            O[dsub] = MFMA16(vf1, P1.v, O[dsub], 0, 0, 0);
        }
        __builtin_amdgcn_s_setprio(0);

        bw = bwN;
        // counted wait: only tile it+1's 3 loads must have landed
        asm volatile("s_waitcnt vmcnt(3)" ::: "memory");
        __builtin_amdgcn_s_barrier();
        __builtin_amdgcn_sched_barrier(0);
        cc += BUFB; if (cc == 3 * BUFB) cc = 0;
        cs += BUFB; if (cs == 3 * BUFB) cs = 0;
    }

    // ---- finish l (cross-lane), normalize + store bf16 tiled AO ----
    l += __shfl_xor(l, 16);
    l += __shfl_xor(l, 32);
    const float rl = 1.f / l;
    const int row = bb * 2048 + q;
    const int r128 = row & 127;
    const int xr = (r128 >> 1) & 3;
    unsigned short* __restrict__ ab = AOb + ((size_t)(row >> 7)) * 65536
                                    + r128 * 32 + (g & 1) * 4;
#pragma unroll
    for (int dsub = 0; dsub < 4; ++dsub) {
        const f32x4 o = O[dsub] * rl;
        const int ch = hh * 2 + (dsub >> 1);
        const int slot = ((dsub & 1) * 2 + (g >> 1)) ^ xr;
        u16x4 pk;
#pragma unroll
        for (int c = 0; c < 4; ++c) pk[c] = f2bf(o[c]);
        *(u16x4*)(ab + (size_t)ch * 4096 + slot * 8) = pk;
    }
#undef STAGE
}

// ---------------------------------------------------------------------------
// Kernel 4: MFMA epilogue GEMM AObf[8192,512] @ WO[512,384pad] -> out fp32.
// grid (128 row-tiles of 64, 3 col-tiles of 128), block 256 = 4 waves (1x4).
// ---------------------------------------------------------------------------
__global__ __launch_bounds__(256) void epi_mfma_kernel(
    const unsigned short* __restrict__ AOb, const unsigned short* __restrict__ WOT,
    float* __restrict__ out)
{
    const int stile = blockIdx.x, jtile = blockIdx.y;
    const int tid = threadIdx.x, wv = tid >> 6, lane = tid & 63;
    const int li = lane & 15, g = lane >> 4;

    __shared__ __align__(16) char LBe[24576];   // 2 bufs x (A 4KB | W 8KB)

    const unsigned short* __restrict__ pA =
        AOb + (size_t)(stile >> 1) * 65536 + (stile & 1) * 2048 + tid * 8;
    const unsigned short* __restrict__ pW = WOT + (size_t)jtile * 65536 + tid * 8;

#define STAGEE(ch, bofs) {                                                    \
        char* dbA = LBe + (bofs) + wv * 1024;                                 \
        const size_t co = (size_t)(ch) * 4096;                                \
        gload16(pA + co,        dbA);                                         \
        gload16(pW + co,        dbA + 4096);                                  \
        gload16(pW + co + 2048, dbA + 8192);                                  \
    }

    int offA[4], offW[2];
#pragma unroll
    for (int ssub = 0; ssub < 4; ++ssub) {
        const int r = ssub * 16 + li;
        offA[ssub] = r * 64 + ((g ^ ((r >> 1) & 3)) << 4);
    }
#pragma unroll
    for (int jsub = 0; jsub < 2; ++jsub) {
        const int n = wv * 32 + jsub * 16 + li;
        offW[jsub] = 4096 + n * 64 + ((g ^ ((n >> 1) & 3)) << 4);
    }

    f32x4 acc[4][2];
#pragma unroll
    for (int i = 0; i < 4; ++i)
#pragma unroll
        for (int j = 0; j < 2; ++j) acc[i][j] = (f32x4){0.f, 0.f, 0.f, 0.f};

    STAGEE(0, 0)
    __syncthreads();

#pragma unroll 1
    for (int ch = 0; ch < 16; ++ch) {
        const int bofs = (ch & 1) * 12288;
        if (ch < 15) STAGEE(ch + 1, bofs ^ 12288)
        const char* bp = LBe + bofs;
        s16x8 ah[4], wh[2];
#pragma unroll
        for (int ssub = 0; ssub < 4; ++ssub)
            ah[ssub] = *(const s16x8*)(bp + offA[ssub]);
#pragma unroll
        for (int jsub = 0; jsub < 2; ++jsub)
            wh[jsub] = *(const s16x8*)(bp + offW[jsub]);
        __builtin_amdgcn_s_setprio(1);
#pragma unroll
        for (int ssub = 0; ssub < 4; ++ssub)
#pragma unroll
            for (int jsub = 0; jsub < 2; ++jsub)
                acc[ssub][jsub] = MFMA16(ah[ssub], wh[jsub], acc[ssub][jsub], 0, 0, 0);
        __builtin_amdgcn_s_setprio(0);
        __syncthreads();
    }
#undef STAGEE

    const int nbase = jtile * 128 + wv * 32 + li;
    const int rbase = stile * 64 + 4 * g;
#pragma unroll
    for (int jsub = 0; jsub < 2; ++jsub) {
        const int o = nbase + jsub * 16;
        if (o < HIDIN) {
#pragma unroll
            for (int ssub = 0; ssub < 4; ++ssub) {
                const f32x4 v = acc[ssub][jsub];
                const int r0 = rbase + ssub * 16;
#pragma unroll
                for (int r = 0; r < 4; ++r)
                    out[(size_t)(r0 + r) * HIDIN + o] = v[r];
            }
        }
    }
}

// ---------------------------------------------------------------------------
extern "C" void kernel_launch(void* const* d_in, const int* in_sizes, int n_in,
                              void* d_out, int out_size, void* d_ws, size_t ws_size,
                              hipStream_t stream)
{
    const float* en  = (const float*)d_in[0];
    const float* de  = (const float*)d_in[1];
    const int*   mask = (const int*)d_in[2];
    const float* WQ  = (const float*)d_in[3];
    const float* WK  = (const float*)d_in[4];
    const float* WV  = (const float*)d_in[5];
    const float* WO  = (const float*)d_in[6];
    float* out = (float*)d_out;

    unsigned short* ws2 = (unsigned short*)d_ws;
    unsigned short* Qh  = ws2 + OF_QH;
    unsigned short* Ql  = ws2 + OF_QL;
    unsigned short* KhT = ws2 + OF_KH;
    unsigned short* KlT = ws2 + OF_KL;
    unsigned short* VtT = ws2 + OF_VT;
    unsigned long long* BiasB = (unsigned long long*)(ws2 + OF_BB);
    unsigned short* CA  = ws2 + OF_CA;
    unsigned short* CW  = ws2 + OF_CW;
    unsigned short* WOT = ws2 + OF_WOT;
    unsigned short* AOb = CA;    // aliases conv-A area (dead after proj)

    bias_kernel<<<dim3(256), 256, 0, stream>>>(mask, BiasB);
    convA_kernel<<<dim3(320, 2), 256, 0, stream>>>(de, en, CA);
    convW_kernel<<<dim3(672), 256, 0, stream>>>(WQ, WK, WV, WO, CW, WOT);
    proj_mfma_kernel<<<dim3(64, 4, 3), 256, 0, stream>>>(CA, CW, Qh, Ql, KhT, KlT, VtT);
    attn_mfma_kernel<<<dim3(16, 32), 512, 0, stream>>>(Qh, Ql, KhT, KlT, VtT,
                                                       (const unsigned short*)BiasB, AOb);
    epi_mfma_kernel<<<dim3(128, 3), 256, 0, stream>>>(AOb, WOT, out);
}

// Round 8
// 187.793 us; speedup vs baseline: 5.0768x; 1.0177x over previous
//
#include <hip/hip_runtime.h>
#include <hip/hip_bf16.h>
#include <math.h>

#define B_      4
#define SD_     2048
#define SE_     2048
#define HIDIN   300
#define HIDMID  512
#define NH      8
#define DH      64
#define ESZ     ((size_t)4194304)          // elems per [32][2048][64] tensor
#define BUFB    24576                       // bytes per attn LDS buffer (Kh+Kl+V)

typedef __attribute__((ext_vector_type(8))) short          s16x8;
typedef __attribute__((ext_vector_type(8))) unsigned short u16x8;
typedef __attribute__((ext_vector_type(4))) unsigned short u16x4;
typedef __attribute__((ext_vector_type(4))) float          f32x4;

#define MFMA16 __builtin_amdgcn_mfma_f32_16x16x32_bf16

// logit scale: (1/sqrt(300)) * log2(e)  -> softmax done in base-2
#define QSCALE  0.0832940411f
#define NEGL   -1.4426950e9f               // -1e9 * log2e
#define DEFER_THR 24.0f                    // defer-max threshold (base-2 units)

__device__ __forceinline__ unsigned short f2bf(float f) {
    unsigned int u = __float_as_uint(f);
    u += 0x7fffu + ((u >> 16) & 1u);          // RNE
    return (unsigned short)(u >> 16);
}
__device__ __forceinline__ float bf2f(unsigned short s) {
    return __uint_as_float((unsigned int)s << 16);
}
__device__ __forceinline__ void gload16(const void* g, void* l) {
    __builtin_amdgcn_global_load_lds(
        (const __attribute__((address_space(1))) void*)g,
        (__attribute__((address_space(3))) void*)l, 16, 0, 0);
}

// ws ushort offsets
#define OF_QH   ((size_t)0)
#define OF_QL   (ESZ)
#define OF_KH   (2*ESZ)
#define OF_KL   (3*ESZ)
#define OF_VT   (4*ESZ)
#define OF_CA   (5*ESZ)                    // deH,deL,enH,enL (4 x 2621440)
#define OF_CW   (OF_CA + 10485760)         // WQh,WQl,WKh,WKl,WVh,WVl (6 x 163840)
#define OF_WOT  (OF_CW + 983040)           // 196608

// ---------------------------------------------------------------------------
// Kernel 0 (runs AFTER proj; lives in dead conv-A ws): mask (int32) ->
// packed-bf16-pair bias table {0, NEGL}. Per (q, 64-t tile, g): 16 bf16 = 8 u32,
// elem idx = sub*4+c  <->  t = sub*16 + g*4 + c.
// addr(u32) = ((((q>>4)*32 + tile)*4 + g)*16 + (q&15))*8
// ---------------------------------------------------------------------------
__global__ __launch_bounds__(256) void bias_kernel(const int* __restrict__ mask,
                                                   unsigned int* __restrict__ BiasT)
{
    const int idx = blockIdx.x * 256 + threadIdx.x;    // 65536 threads
    const int q = idx >> 5, tile = idx & 31;
    const int* __restrict__ mrow = mask + (size_t)q * SE_ + tile * 64;
    const unsigned int NEGB = (unsigned int)f2bf(NEGL);
    const int qblk = q >> 4, qlo = q & 15;
#pragma unroll
    for (int g = 0; g < 4; ++g) {
        unsigned int w[8];
#pragma unroll
        for (int sub = 0; sub < 4; ++sub) {
            const int4 mm = *(const int4*)(mrow + sub * 16 + g * 4);
            w[sub * 2]     = (mm.x ? NEGB : 0u) | ((mm.y ? NEGB : 0u) << 16);
            w[sub * 2 + 1] = (mm.z ? NEGB : 0u) | ((mm.w ? NEGB : 0u) << 16);
        }
        unsigned int* dst = BiasT +
            ((((size_t)qblk * 32 + tile) * 4 + g) * 16 + qlo) * 8;
        *(uint4*)dst       = make_uint4(w[0], w[1], w[2], w[3]);
        *(uint4*)(dst + 4) = make_uint4(w[4], w[5], w[6], w[7]);
    }
}

// ---------------------------------------------------------------------------
// Kernel 1a: de/en fp32 -> split bf16 hi/lo, tiled GEMM-A layout.
// ---------------------------------------------------------------------------
__global__ __launch_bounds__(256) void convA_kernel(
    const float* __restrict__ de, const float* __restrict__ en,
    unsigned short* __restrict__ CA)
{
    const int idx = blockIdx.x * 256 + threadIdx.x;    // 81920 per matrix
    const int mat = blockIdx.y;
    const float* __restrict__ A = mat ? en : de;
    unsigned short* __restrict__ H = CA + (size_t)mat * 5242880;
    unsigned short* __restrict__ L = H + 2621440;
    const int row = idx / 10, ch = idx - row * 10;
    float v[32];
    if (ch < 9) {
#pragma unroll
        for (int i = 0; i < 8; ++i) {
            const float4 f = *(const float4*)(A + (size_t)row * 300 + ch * 32 + i * 4);
            v[i*4+0] = f.x; v[i*4+1] = f.y; v[i*4+2] = f.z; v[i*4+3] = f.w;
        }
    } else {
#pragma unroll
        for (int i = 0; i < 32; ++i) {
            const int k = 288 + i;
            v[i] = (k < 300) ? A[(size_t)row * 300 + k] : 0.f;
        }
    }
    const int r128 = row & 127;
    const int xr = (r128 >> 1) & 3;
    const size_t tb = ((size_t)(row >> 7) * 10 + ch) * 4096 + r128 * 32;
#pragma unroll
    for (int sub = 0; sub < 4; ++sub) {
        const int slot = sub ^ xr;
        u16x8 hv, lv;
#pragma unroll
        for (int e = 0; e < 8; ++e) {
            const float f = v[sub * 8 + e];
            const unsigned short h = f2bf(f);
            hv[e] = h; lv[e] = f2bf(f - bf2f(h));
        }
        *(u16x8*)(H + tb + slot * 8) = hv;
        *(u16x8*)(L + tb + slot * 8) = lv;
    }
}

// ---------------------------------------------------------------------------
// Kernel 1b: WQ/WK/WV -> split bf16 transposed tiled B layout (QSCALE folded
// into WQ); WO -> plain bf16 transposed tiled (n padded 300->384).
// ---------------------------------------------------------------------------
__global__ __launch_bounds__(256) void convW_kernel(
    const float* __restrict__ WQ, const float* __restrict__ WK,
    const float* __restrict__ WV, const float* __restrict__ WO,
    unsigned short* __restrict__ CW, unsigned short* __restrict__ WOT)
{
    const int idx = blockIdx.x * 256 + threadIdx.x;
    if (idx < 122880) {                       // QKV: which x k(320) x n4(128)
        const int which = idx / 40960;
        const int rem = idx - which * 40960;
        const int k = rem >> 7;
        const int n0 = (rem & 127) * 4;
        const float* __restrict__ W = which == 0 ? WQ : (which == 1 ? WK : WV);
        unsigned short* __restrict__ H = CW + (size_t)which * 327680;
        unsigned short* __restrict__ L = H + 163840;
        const float sc = (which == 0) ? QSCALE : 1.f;
        float4 w = make_float4(0.f, 0.f, 0.f, 0.f);
        if (k < 300) w = *(const float4*)(W + (size_t)k * 512 + n0);
        const float wv4[4] = {w.x * sc, w.y * sc, w.z * sc, w.w * sc};
        const int ch = k >> 5, kk = k & 31;
#pragma unroll
        for (int j = 0; j < 4; ++j) {
            const int n = n0 + j, ntile = n >> 7, nr = n & 127;
            const size_t o = ((size_t)(ntile * 10 + ch) * 128 + nr) * 32
                           + (((kk >> 3) ^ ((nr >> 1) & 3)) << 3) + (kk & 7);
            const unsigned short h = f2bf(wv4[j]);
            H[o] = h; L[o] = f2bf(wv4[j] - bf2f(h));
        }
    } else {                                   // WO: k(512) x n4(96)
        const int idx2 = idx - 122880;
        const int k = idx2 / 96, n4 = idx2 - k * 96;
        const int n0 = n4 * 4;
        float4 w = make_float4(0.f, 0.f, 0.f, 0.f);
        if (n0 < 300) w = *(const float4*)(WO + (size_t)k * 300 + n0);
        const float wv4[4] = {w.x, w.y, w.z, w.w};
        const int ch = k >> 5, kk = k & 31;
#pragma unroll
        for (int j = 0; j < 4; ++j) {
            const int n = n0 + j, ntile = n >> 7, nr = n & 127;
            const size_t o = ((size_t)(ntile * 16 + ch) * 128 + nr) * 32
                           + (((kk >> 3) ^ ((nr >> 1) & 3)) << 3) + (kk & 7);
            WOT[o] = f2bf(wv4[j]);
        }
    }
}

// ---------------------------------------------------------------------------
// Kernel 2: MFMA QKV projection, 3-term split bf16.
// ---------------------------------------------------------------------------
__global__ __launch_bounds__(256) void proj_mfma_kernel(
    const unsigned short* __restrict__ CA, const unsigned short* __restrict__ CW,
    unsigned short* __restrict__ Qh, unsigned short* __restrict__ Ql,
    unsigned short* __restrict__ KhT, unsigned short* __restrict__ KlT,
    unsigned short* __restrict__ VtT)
{
    const int stile = blockIdx.x, jtile = blockIdx.y, which = blockIdx.z;
    const int tid = threadIdx.x, wv = tid >> 6, lane = tid & 63;
    const int li = lane & 15, g = lane >> 4;
    const int wr = wv >> 1, wc = wv & 1;

    __shared__ __align__(16) char LBp[65536];   // 2 bufs x (Ah|Al|Wh|Wl) x 8KB

    const unsigned short* __restrict__ pAh =
        CA + (size_t)(which ? 1 : 0) * 5242880 + (size_t)stile * 40960 + tid * 8;
    const unsigned short* __restrict__ pAl = pAh + 2621440;
    const unsigned short* __restrict__ pWh =
        CW + (size_t)which * 327680 + (size_t)jtile * 40960 + tid * 8;
    const unsigned short* __restrict__ pWl = pWh + 163840;

#define STAGEP(ch, bofs) {                                                    \
        char* db = LBp + (bofs) + wv * 1024;                                  \
        const size_t co = (size_t)(ch) * 4096;                                \
        gload16(pAh + co,        db);                                         \
        gload16(pAh + co + 2048, db + 4096);                                  \
        gload16(pAl + co,        db + 8192);                                  \
        gload16(pAl + co + 2048, db + 12288);                                 \
        gload16(pWh + co,        db + 16384);                                 \
        gload16(pWh + co + 2048, db + 20480);                                 \
        gload16(pWl + co,        db + 24576);                                 \
        gload16(pWl + co + 2048, db + 28672);                                 \
    }

    int offA[4], offW[4];
#pragma unroll
    for (int ssub = 0; ssub < 4; ++ssub) {
        const int r = wr * 64 + ssub * 16 + li;
        offA[ssub] = r * 64 + ((g ^ ((r >> 1) & 3)) << 4);
    }
#pragma unroll
    for (int jsub = 0; jsub < 4; ++jsub) {
        const int n = wc * 64 + jsub * 16 + li;
        offW[jsub] = n * 64 + ((g ^ ((n >> 1) & 3)) << 4);
    }

    f32x4 acc[4][4];
#pragma unroll
    for (int i = 0; i < 4; ++i)
#pragma unroll
        for (int j = 0; j < 4; ++j) acc[i][j] = (f32x4){0.f, 0.f, 0.f, 0.f};

    STAGEP(0, 0)
    __syncthreads();

#pragma unroll 1
    for (int ch = 0; ch < 10; ++ch) {
        const int bofs = (ch & 1) * 32768;
        if (ch < 9) STAGEP(ch + 1, bofs ^ 32768)
        const char* bp = LBp + bofs;
        s16x8 ah[4], al[4], wh[4], wl[4];
#pragma unroll
        for (int ssub = 0; ssub < 4; ++ssub) {
            ah[ssub] = *(const s16x8*)(bp + offA[ssub]);
            al[ssub] = *(const s16x8*)(bp + 8192 + offA[ssub]);
        }
#pragma unroll
        for (int jsub = 0; jsub < 4; ++jsub) {
            wh[jsub] = *(const s16x8*)(bp + 16384 + offW[jsub]);
            wl[jsub] = *(const s16x8*)(bp + 24576 + offW[jsub]);
        }
        __builtin_amdgcn_s_setprio(1);
#pragma unroll
        for (int ssub = 0; ssub < 4; ++ssub)
#pragma unroll
            for (int jsub = 0; jsub < 4; ++jsub) {
                acc[ssub][jsub] = MFMA16(ah[ssub], wh[jsub], acc[ssub][jsub], 0, 0, 0);
                acc[ssub][jsub] = MFMA16(ah[ssub], wl[jsub], acc[ssub][jsub], 0, 0, 0);
                acc[ssub][jsub] = MFMA16(al[ssub], wh[jsub], acc[ssub][jsub], 0, 0, 0);
            }
        __builtin_amdgcn_s_setprio(0);
        __syncthreads();
    }
#undef STAGEP

    const int jgbase = jtile * 128 + wc * 64 + li;
    const int sbase0 = stile * 128 + wr * 64 + 4 * g;
#pragma unroll
    for (int jsub = 0; jsub < 4; ++jsub) {
        const int jgg = jgbase + jsub * 16;
        const int d = jgg >> 3, hh = jgg & 7;
#pragma unroll
        for (int ssub = 0; ssub < 4; ++ssub) {
            const f32x4 v = acc[ssub][jsub];
            const int sg0 = sbase0 + ssub * 16;
            const int bbv = sg0 >> 11;
            const int bhn = bbv * 8 + hh;
            const int sl0 = sg0 & 2047;
            if (which == 0) {
                const size_t o = ((size_t)bhn * 2048 + sl0) * 64 + d;
#pragma unroll
                for (int r = 0; r < 4; ++r) {
                    const float val = v[r];
                    const unsigned short hi = f2bf(val);
                    Qh[o + r * 64] = hi;
                    Ql[o + r * 64] = f2bf(val - bf2f(hi));
                }
            } else if (which == 1) {
                const int tile = sl0 >> 6, tt0 = sl0 & 63;
                const size_t tb = ((size_t)(bhn * 32 + tile)) << 12;
#pragma unroll
                for (int r = 0; r < 4; ++r) {
                    const int tt = tt0 + r;
                    const size_t o = tb + tt * 64 + (((d >> 3) ^ (tt & 7)) << 3) + (d & 7);
                    const float val = v[r];
                    const unsigned short hi = f2bf(val);
                    KhT[o] = hi;
                    KlT[o] = f2bf(val - bf2f(hi));
                }
            } else {
                const int tile = sl0 >> 6, tin0 = sl0 & 63;
                const size_t tb = ((size_t)(bhn * 32 + tile)) << 12;
                const int blk = tin0 >> 5, gg2 = (tin0 >> 2) & 3, half = (tin0 >> 4) & 1;
                const size_t o = tb + (size_t)d * 64
                               + ((((blk << 2) | gg2) ^ (d & 7)) << 3) + half * 4;
                u16x4 pk;
#pragma unroll
                for (int r = 0; r < 4; ++r) pk[r] = f2bf(v[r]);
                *(u16x4*)(VtT + o) = pk;
            }
        }
    }
}

// ---------------------------------------------------------------------------
// Kernel 3: MFMA flash attention. 4 waves x 32 q-rows (2 q-sets/wave),
// 3-buffer ring + counted vmcnt, setprio, XCD swizzle, defer-max,
// bias from packed-bf16 table, l via ones-MFMA.
// ---------------------------------------------------------------------------
__global__ __launch_bounds__(256, 2) void attn_mfma_kernel(
    const unsigned short* __restrict__ Qh, const unsigned short* __restrict__ Ql,
    const unsigned short* __restrict__ KhT, const unsigned short* __restrict__ KlT,
    const unsigned short* __restrict__ VtT, const unsigned int* __restrict__ BiasT,
    unsigned short* __restrict__ AOb)
{
    const int lin = blockIdx.x + 16 * blockIdx.y;
    const int qt = (lin >> 3) & 15;
    const int bh = (lin & 7) + ((lin >> 7) << 3);
    const int bb = bh >> 3, hh = bh & 7;
    const int tid = threadIdx.x;
    const int wv = tid >> 6, lane = tid & 63;
    const int g = lane >> 4, li = lane & 15;
    const int q0r = qt * 128 + wv * 16 + li;          // qset0 row; qset1 = +64

    __shared__ __align__(16) char LB[3 * BUFB];

    // Q fragments, both qsets
    const size_t qoff = ((size_t)bh * SD_ + q0r) * DH + 8 * g;
    const s16x8 qh0_0 = *(const s16x8*)(Qh + qoff);
    const s16x8 qh1_0 = *(const s16x8*)(Qh + qoff + 32);
    const s16x8 ql0_0 = *(const s16x8*)(Ql + qoff);
    const s16x8 ql1_0 = *(const s16x8*)(Ql + qoff + 32);
    const s16x8 qh0_1 = *(const s16x8*)(Qh + qoff + 4096);
    const s16x8 qh1_1 = *(const s16x8*)(Qh + qoff + 4128);
    const s16x8 ql0_1 = *(const s16x8*)(Ql + qoff + 4096);
    const s16x8 ql1_1 = *(const s16x8*)(Ql + qoff + 4128);

    const unsigned short* __restrict__ sKh = KhT + ((size_t)bh << 17) + tid * 8;
    const unsigned short* __restrict__ sKl = KlT + ((size_t)bh << 17) + tid * 8;
    const unsigned short* __restrict__ sVt = VtT + ((size_t)bh << 17) + tid * 8;

    const int base0 = li * 128 + ((g ^ (li & 7)) << 4);
    const int base1 = li * 128 + (((4 + g) ^ (li & 7)) << 4);

    // bias table bases (u32 units) for qset 0/1
    const size_t bb0 = ((((size_t)(qt * 8 + 0 * 4 + wv)) * 32) * 4 + g) * 16 * 8 + li * 8;
    const size_t bb1 = ((((size_t)(qt * 8 + 1 * 4 + wv)) * 32) * 4 + g) * 16 * 8 + li * 8;
    // per-tile stride in u32: 4 g * 16 q * 8 = 512
#define BIASLOAD(T, R0A, R0B, R1A, R1B) {                                     \
        const uint4* p0 = (const uint4*)(BiasT + bb0 + (size_t)(T) * 512);    \
        R0A = p0[0]; R0B = p0[1];                                             \
        const uint4* p1 = (const uint4*)(BiasT + bb1 + (size_t)(T) * 512);    \
        R1A = p1[0]; R1B = p1[1];                                             \
    }

#define STAGE(tile, boff)                                                     \
    {                                                                         \
        char* db = LB + (boff) + wv * 1024;                                   \
        const size_t toff = (size_t)(tile) << 12;                             \
        gload16(sKh + toff,        db);                                       \
        gload16(sKh + toff + 2048, db + 4096);                                \
        gload16(sKl + toff,        db + 8192);                                \
        gload16(sKl + toff + 2048, db + 12288);                               \
        gload16(sVt + toff,        db + 16384);                               \
        gload16(sVt + toff + 2048, db + 20480);                               \
    }

    float m0 = -INFINITY, m1 = -INFINITY;
    f32x4 O0[4], O1[4], lacc0, lacc1;
#pragma unroll
    for (int i = 0; i < 4; ++i) {
        O0[i] = (f32x4){0.f, 0.f, 0.f, 0.f};
        O1[i] = (f32x4){0.f, 0.f, 0.f, 0.f};
    }
    lacc0 = (f32x4){0.f, 0.f, 0.f, 0.f};
    lacc1 = (f32x4){0.f, 0.f, 0.f, 0.f};

    s16x8 ones;
#pragma unroll
    for (int i = 0; i < 8; ++i) ones[i] = (short)0x3F80;

    uint4 cA0, cA1, cB0, cB1;     // current bias (qset0: A0/A1, qset1: B0/B1)
    uint4 nA0, nA1, nB0, nB1;     // next

    STAGE(0, 0)
    BIASLOAD(0, cA0, cA1, cB0, cB1)
    STAGE(1, BUFB)
    asm volatile("s_waitcnt vmcnt(6)" ::: "memory");
    __builtin_amdgcn_s_barrier();
    __builtin_amdgcn_sched_barrier(0);

    int cc = 0, cs = 2 * BUFB;

#define UNPK(W, S, sub, cbase)                                                \
        S[sub][cbase]     = __uint_as_float((W) << 16);                       \
        S[sub][cbase + 1] = __uint_as_float((W) & 0xFFFF0000u);

#define ITER(IT, C0A, C0B, C1A, C1B, N0A, N0B, N1A, N1B)                      \
    {                                                                         \
        f32x4 s0[4], s1[4];                                                   \
        UNPK(C0A.x, s0, 0, 0) UNPK(C0A.y, s0, 0, 2)                           \
        UNPK(C0A.z, s0, 1, 0) UNPK(C0A.w, s0, 1, 2)                           \
        UNPK(C0B.x, s0, 2, 0) UNPK(C0B.y, s0, 2, 2)                           \
        UNPK(C0B.z, s0, 3, 0) UNPK(C0B.w, s0, 3, 2)                           \
        UNPK(C1A.x, s1, 0, 0) UNPK(C1A.y, s1, 0, 2)                           \
        UNPK(C1A.z, s1, 1, 0) UNPK(C1A.w, s1, 1, 2)                           \
        UNPK(C1B.x, s1, 2, 0) UNPK(C1B.y, s1, 2, 2)                           \
        UNPK(C1B.z, s1, 3, 0) UNPK(C1B.w, s1, 3, 2)                           \
        BIASLOAD(((IT) + 1) & 31, N0A, N0B, N1A, N1B)                         \
        __builtin_amdgcn_s_setprio(1);                                        \
        _Pragma("unroll")                                                     \
        for (int sub = 0; sub < 4; ++sub) {                                   \
            const s16x8 kh0 = *(const s16x8*)(LB + cc + base0 + sub * 2048);  \
            const s16x8 kh1 = *(const s16x8*)(LB + cc + base1 + sub * 2048);  \
            const s16x8 kl0 = *(const s16x8*)(LB + cc + base0 + 8192 + sub * 2048); \
            const s16x8 kl1 = *(const s16x8*)(LB + cc + base1 + 8192 + sub * 2048); \
            s0[sub] = MFMA16(kh0, qh0_0, s0[sub], 0, 0, 0);                   \
            s0[sub] = MFMA16(kh0, ql0_0, s0[sub], 0, 0, 0);                   \
            s0[sub] = MFMA16(kl0, qh0_0, s0[sub], 0, 0, 0);                   \
            s0[sub] = MFMA16(kh1, qh1_0, s0[sub], 0, 0, 0);                   \
            s0[sub] = MFMA16(kh1, ql1_0, s0[sub], 0, 0, 0);                   \
            s0[sub] = MFMA16(kl1, qh1_0, s0[sub], 0, 0, 0);                   \
            s1[sub] = MFMA16(kh0, qh0_1, s1[sub], 0, 0, 0);                   \
            s1[sub] = MFMA16(kh0, ql0_1, s1[sub], 0, 0, 0);                   \
            s1[sub] = MFMA16(kl0, qh0_1, s1[sub], 0, 0, 0);                   \
            s1[sub] = MFMA16(kh1, qh1_1, s1[sub], 0, 0, 0);                   \
            s1[sub] = MFMA16(kh1, ql1_1, s1[sub], 0, 0, 0);                   \
            s1[sub] = MFMA16(kl1, qh1_1, s1[sub], 0, 0, 0);                   \
        }                                                                     \
        __builtin_amdgcn_s_setprio(0);                                        \
        float t0, t1;                                                         \
        {                                                                     \
            float a = fmaxf(s0[0][0], fmaxf(s0[0][1], s0[0][2]));             \
            float b = fmaxf(s0[0][3], fmaxf(s0[1][0], s0[1][1]));             \
            float c = fmaxf(s0[1][2], fmaxf(s0[1][3], s0[2][0]));             \
            float d = fmaxf(s0[2][1], fmaxf(s0[2][2], s0[2][3]));             \
            float e = fmaxf(s0[3][0], fmaxf(s0[3][1], s0[3][2]));             \
            t0 = fmaxf(fmaxf(a, fmaxf(b, c)), fmaxf(s0[3][3], fmaxf(d, e)));  \
        }                                                                     \
        {                                                                     \
            float a = fmaxf(s1[0][0], fmaxf(s1[0][1], s1[0][2]));             \
            float b = fmaxf(s1[0][3], fmaxf(s1[1][0], s1[1][1]));             \
            float c = fmaxf(s1[1][2], fmaxf(s1[1][3], s1[2][0]));             \
            float d = fmaxf(s1[2][1], fmaxf(s1[2][2], s1[2][3]));             \
            float e = fmaxf(s1[3][0], fmaxf(s1[3][1], s1[3][2]));             \
            t1 = fmaxf(fmaxf(a, fmaxf(b, c)), fmaxf(s1[3][3], fmaxf(d, e)));  \
        }                                                                     \
        const int okd = (t0 <= m0 + DEFER_THR) && (t1 <= m1 + DEFER_THR);     \
        if (!__all(okd)) {                                                    \
            float r0 = fmaxf(t0, __shfl_xor(t0, 16));                         \
            r0 = fmaxf(r0, __shfl_xor(r0, 32));                               \
            float r1 = fmaxf(t1, __shfl_xor(t1, 16));                         \
            r1 = fmaxf(r1, __shfl_xor(r1, 32));                               \
            const float mn0 = fmaxf(m0, r0), mn1 = fmaxf(m1, r1);             \
            const float sc0 = exp2f(m0 - mn0), sc1 = exp2f(m1 - mn1);         \
            m0 = mn0; m1 = mn1;                                               \
            _Pragma("unroll")                                                 \
            for (int i = 0; i < 4; ++i) { O0[i] *= sc0; O1[i] *= sc1; }       \
            lacc0 *= sc0; lacc1 *= sc1;                                       \
        }                                                                     \
        _Pragma("unroll")                                                     \
        for (int sub = 0; sub < 4; ++sub)                                     \
            _Pragma("unroll")                                                 \
            for (int c = 0; c < 4; ++c) {                                     \
                s0[sub][c] = exp2f(s0[sub][c] - m0);                          \
                s1[sub][c] = exp2f(s1[sub][c] - m1);                          \
            }                                                                 \
        union { s16x8 v; unsigned int w[4]; } P00, P10, P01, P11;             \
        asm("v_cvt_pk_bf16_f32 %0, %1, %2" : "=v"(P00.w[0]) : "v"(s0[0][0]), "v"(s0[0][1])); \
        asm("v_cvt_pk_bf16_f32 %0, %1, %2" : "=v"(P00.w[1]) : "v"(s0[0][2]), "v"(s0[0][3])); \
        asm("v_cvt_pk_bf16_f32 %0, %1, %2" : "=v"(P00.w[2]) : "v"(s0[1][0]), "v"(s0[1][1])); \
        asm("v_cvt_pk_bf16_f32 %0, %1, %2" : "=v"(P00.w[3]) : "v"(s0[1][2]), "v"(s0[1][3])); \
        asm("v_cvt_pk_bf16_f32 %0, %1, %2" : "=v"(P10.w[0]) : "v"(s0[2][0]), "v"(s0[2][1])); \
        asm("v_cvt_pk_bf16_f32 %0, %1, %2" : "=v"(P10.w[1]) : "v"(s0[2][2]), "v"(s0[2][3])); \
        asm("v_cvt_pk_bf16_f32 %0, %1, %2" : "=v"(P10.w[2]) : "v"(s0[3][0]), "v"(s0[3][1])); \
        asm("v_cvt_pk_bf16_f32 %0, %1, %2" : "=v"(P10.w[3]) : "v"(s0[3][2]), "v"(s0[3][3])); \
        asm("v_cvt_pk_bf16_f32 %0, %1, %2" : "=v"(P01.w[0]) : "v"(s1[0][0]), "v"(s1[0][1])); \
        asm("v_cvt_pk_bf16_f32 %0, %1, %2" : "=v"(P01.w[1]) : "v"(s1[0][2]), "v"(s1[0][3])); \
        asm("v_cvt_pk_bf16_f32 %0, %1, %2" : "=v"(P01.w[2]) : "v"(s1[1][0]), "v"(s1[1][1])); \
        asm("v_cvt_pk_bf16_f32 %0, %1, %2" : "=v"(P01.w[3]) : "v"(s1[1][2]), "v"(s1[1][3])); \
        asm("v_cvt_pk_bf16_f32 %0, %1, %2" : "=v"(P11.w[0]) : "v"(s1[2][0]), "v"(s1[2][1])); \
        asm("v_cvt_pk_bf16_f32 %0, %1, %2" : "=v"(P11.w[1]) : "v"(s1[2][2]), "v"(s1[2][3])); \
        asm("v_cvt_pk_bf16_f32 %0, %1, %2" : "=v"(P11.w[2]) : "v"(s1[3][0]), "v"(s1[3][1])); \
        asm("v_cvt_pk_bf16_f32 %0, %1, %2" : "=v"(P11.w[3]) : "v"(s1[3][2]), "v"(s1[3][3])); \
        __builtin_amdgcn_s_setprio(1);                                        \
        _Pragma("unroll")                                                     \
        for (int dsub = 0; dsub < 4; ++dsub) {                                \
            const s16x8 vf0 = *(const s16x8*)(LB + cc + base0 + 16384 + dsub * 2048); \
            const s16x8 vf1 = *(const s16x8*)(LB + cc + base1 + 16384 + dsub * 2048); \
            O0[dsub] = MFMA16(vf0, P00.v, O0[dsub], 0, 0, 0);                 \
            O0[dsub] = MFMA16(vf1, P10.v, O0[dsub], 0, 0, 0);                 \
            O1[dsub] = MFMA16(vf0, P01.v, O1[dsub], 0, 0, 0);                 \
            O1[dsub] = MFMA16(vf1, P11.v, O1[dsub], 0, 0, 0);                 \
        }                                                                     \
        lacc0 = MFMA16(ones, P00.v, lacc0, 0, 0, 0);                          \
        lacc0 = MFMA16(ones, P10.v, lacc0, 0, 0, 0);                          \
        lacc1 = MFMA16(ones, P01.v, lacc1, 0, 0, 0);                          \
        lacc1 = MFMA16(ones, P11.v, lacc1, 0, 0, 0);                          \
        __builtin_amdgcn_s_setprio(0);                                        \
        STAGE(((IT) + 2) & 31, cs)                                            \
        asm volatile("s_waitcnt vmcnt(6)" ::: "memory");                      \
        __builtin_amdgcn_s_barrier();                                         \
        __builtin_amdgcn_sched_barrier(0);                                    \
        cc += BUFB; if (cc == 3 * BUFB) cc = 0;                               \
        cs += BUFB; if (cs == 3 * BUFB) cs = 0;                               \
    }

#pragma unroll 1
    for (int itp = 0; itp < 32; itp += 2) {
        ITER(itp,     cA0, cA1, cB0, cB1, nA0, nA1, nB0, nB1)
        ITER(itp + 1, nA0, nA1, nB0, nB1, cA0, cA1, cB0, cB1)
    }

    // ---- normalize + store both q-rows (bf16 tiled AO layout) ----
#pragma unroll
    for (int qs = 0; qs < 2; ++qs) {
        const float rl = 1.f / (qs ? lacc1[0] : lacc0[0]);
        const f32x4* Oq = qs ? O1 : O0;
        const int row = bb * 2048 + qt * 128 + qs * 64 + wv * 16 + li;
        const int r128 = row & 127;
        const int xr = (r128 >> 1) & 3;
        unsigned short* __restrict__ ab = AOb + ((size_t)(row >> 7)) * 65536
                                        + r128 * 32 + (g & 1) * 4;
#pragma unroll
        for (int dsub = 0; dsub < 4; ++dsub) {
            const f32x4 o = Oq[dsub] * rl;
            const int ch = hh * 2 + (dsub >> 1);
            const int slot = ((dsub & 1) * 2 + (g >> 1)) ^ xr;
            u16x4 pk;
#pragma unroll
            for (int c = 0; c < 4; ++c) pk[c] = f2bf(o[c]);
            *(u16x4*)(ab + (size_t)ch * 4096 + slot * 8) = pk;
        }
    }
#undef STAGE
#undef BIASLOAD
#undef UNPK
#undef ITER
}

// ---------------------------------------------------------------------------
// Kernel 4: MFMA epilogue GEMM AObf[8192,512] @ WO[512,384pad] -> out fp32.
// ---------------------------------------------------------------------------
__global__ __launch_bounds__(256) void epi_mfma_kernel(
    const unsigned short* __restrict__ AOb, const unsigned short* __restrict__ WOT,
    float* __restrict__ out)
{
    const int stile = blockIdx.x, jtile = blockIdx.y;
    const int tid = threadIdx.x, wv = tid >> 6, lane = tid & 63;
    const int li = lane & 15, g = lane >> 4;

    __shared__ __align__(16) char LBe[24576];   // 2 bufs x (A 4KB | W 8KB)

    const unsigned short* __restrict__ pA =
        AOb + (size_t)(stile >> 1) * 65536 + (stile & 1) * 2048 + tid * 8;
    const unsigned short* __restrict__ pW = WOT + (size_t)jtile * 65536 + tid * 8;

#define STAGEE(ch, bofs) {                                                    \
        char* dbA = LBe + (bofs) + wv * 1024;                                 \
        const size_t co = (size_t)(ch) * 4096;                                \
        gload16(pA + co,        dbA);                                         \
        gload16(pW + co,        dbA + 4096);                                  \
        gload16(pW + co + 2048, dbA + 8192);                                  \
    }

    int offA[4], offW[2];
#pragma unroll
    for (int ssub = 0; ssub < 4; ++ssub) {
        const int r = ssub * 16 + li;
        offA[ssub] = r * 64 + ((g ^ ((r >> 1) & 3)) << 4);
    }
#pragma unroll
    for (int jsub = 0; jsub < 2; ++jsub) {
        const int n = wv * 32 + jsub * 16 + li;
        offW[jsub] = 4096 + n * 64 + ((g ^ ((n >> 1) & 3)) << 4);
    }

    f32x4 acc[4][2];
#pragma unroll
    for (int i = 0; i < 4; ++i)
#pragma unroll
        for (int j = 0; j < 2; ++j) acc[i][j] = (f32x4){0.f, 0.f, 0.f, 0.f};

    STAGEE(0, 0)
    __syncthreads();

#pragma unroll 1
    for (int ch = 0; ch < 16; ++ch) {
        const int bofs = (ch & 1) * 12288;
        if (ch < 15) STAGEE(ch + 1, bofs ^ 12288)
        const char* bp = LBe + bofs;
        s16x8 ah[4], wh[2];
#pragma unroll
        for (int ssub = 0; ssub < 4; ++ssub)
            ah[ssub] = *(const s16x8*)(bp + offA[ssub]);
#pragma unroll
        for (int jsub = 0; jsub < 2; ++jsub)
            wh[jsub] = *(const s16x8*)(bp + offW[jsub]);
        __builtin_amdgcn_s_setprio(1);
#pragma unroll
        for (int ssub = 0; ssub < 4; ++ssub)
#pragma unroll
            for (int jsub = 0; jsub < 2; ++jsub)
                acc[ssub][jsub] = MFMA16(ah[ssub], wh[jsub], acc[ssub][jsub], 0, 0, 0);
        __builtin_amdgcn_s_setprio(0);
        __syncthreads();
    }
#undef STAGEE

    const int nbase = jtile * 128 + wv * 32 + li;
    const int rbase = stile * 64 + 4 * g;
#pragma unroll
    for (int jsub = 0; jsub < 2; ++jsub) {
        const int o = nbase + jsub * 16;
        if (o < HIDIN) {
#pragma unroll
            for (int ssub = 0; ssub < 4; ++ssub) {
                const f32x4 v = acc[ssub][jsub];
                const int r0 = rbase + ssub * 16;
#pragma unroll
                for (int r = 0; r < 4; ++r)
                    out[(size_t)(r0 + r) * HIDIN + o] = v[r];
            }
        }
    }
}

// ---------------------------------------------------------------------------
extern "C" void kernel_launch(void* const* d_in, const int* in_sizes, int n_in,
                              void* d_out, int out_size, void* d_ws, size_t ws_size,
                              hipStream_t stream)
{
    const float* en  = (const float*)d_in[0];
    const float* de  = (const float*)d_in[1];
    const int*   mask = (const int*)d_in[2];
    const float* WQ  = (const float*)d_in[3];
    const float* WK  = (const float*)d_in[4];
    const float* WV  = (const float*)d_in[5];
    const float* WO  = (const float*)d_in[6];
    float* out = (float*)d_out;

    unsigned short* ws2 = (unsigned short*)d_ws;
    unsigned short* Qh  = ws2 + OF_QH;
    unsigned short* Ql  = ws2 + OF_QL;
    unsigned short* KhT = ws2 + OF_KH;
    unsigned short* KlT = ws2 + OF_KL;
    unsigned short* VtT = ws2 + OF_VT;
    unsigned short* CA  = ws2 + OF_CA;
    unsigned short* CW  = ws2 + OF_CW;
    unsigned short* WOT = ws2 + OF_WOT;
    unsigned short* AOb = CA;                                 // aliases conv-A (dead after proj)
    unsigned int*  BiasT = (unsigned int*)(CA + 4194304);     // aliases conv-A tail

    convA_kernel<<<dim3(320, 2), 256, 0, stream>>>(de, en, CA);
    convW_kernel<<<dim3(672), 256, 0, stream>>>(WQ, WK, WV, WO, CW, WOT);
    proj_mfma_kernel<<<dim3(64, 4, 3), 256, 0, stream>>>(CA, CW, Qh, Ql, KhT, KlT, VtT);
    bias_kernel<<<dim3(256), 256, 0, stream>>>(mask, BiasT);  // after proj: CA tail is free
    attn_mfma_kernel<<<dim3(16, 32), 256, 0, stream>>>(Qh, Ql, KhT, KlT, VtT, BiasT, AOb);
    epi_mfma_kernel<<<dim3(128, 3), 256, 0, stream>>>(AOb, WOT, out);
}